// Round 1
// baseline (525.071 us; speedup 1.0000x reference)
//
#include <hip/hip_runtime.h>

#define B_ 16
#define SST 256
#define SL 48
#define VOCAB 16384
#define D_ 64
#define CH 112
#define S_TILE 8

#define T_ELEMS (B_*CH*SST)          // 458752
#define E_ELEMS (B_*D_*SL)           // 49152
#define OUT0_ELEMS ((size_t)B_*SST*VOCAB)
#define OUT1_ELEMS (B_*D_*SST)

// ---------------- gather + cl0 (1x1 conv) ----------------
__global__ void gather_t0_kernel(const int* __restrict__ x,
                                 const float* __restrict__ emb,
                                 const float* __restrict__ cl0_w,
                                 const float* __restrict__ cl0_b,
                                 float* __restrict__ pre_d,   // B,D,SST
                                 float* __restrict__ t0) {    // B,CH,SST
    int bs = blockIdx.x;
    int b = bs / SST, s = bs % SST;
    int tid = threadIdx.x;
    __shared__ float ecol[D_];
    int v = x[b*SST + s];
    if (tid < D_) {
        float e = emb[v*D_ + tid];
        ecol[tid] = e;
        pre_d[(b*D_ + tid)*SST + s] = e;
    }
    __syncthreads();
    if (tid < CH) {
        float acc = cl0_b[tid];
        const float* w = cl0_w + tid*D_;
        #pragma unroll
        for (int d = 0; d < D_; ++d) acc += w[d]*ecol[d];
        t0[(b*CH + tid)*SST + s] = acc;
    }
}

// ---------------- E[b,o,l] = we @ ees + cpr1_b (stage-invariant) ----------------
__global__ void e_kernel(const float* __restrict__ ees,
                         const float* __restrict__ cpr1_w,
                         const float* __restrict__ cpr1_b,
                         float* __restrict__ Eb) {  // B,D,SL
    int bl = blockIdx.x;
    int b = bl / SL, l = bl % SL;
    int tid = threadIdx.x; // 64 threads
    __shared__ float ec[D_];
    ec[tid] = ees[(b*D_ + tid)*SL + l];
    __syncthreads();
    float acc = cpr1_b[tid];
    const float* w = cpr1_w + tid*(2*D_) + D_;
    #pragma unroll
    for (int c = 0; c < D_; ++c) acc += w[c]*ec[c];
    Eb[(b*D_ + tid)*SL + l] = acc;
}

// ---------------- fused stage ----------------
__global__ __launch_bounds__(256) void stage_kernel(
    const float* __restrict__ t_in,
    float* __restrict__ t_out,
    const float* __restrict__ conv_w,  // CH,CH,3
    const float* __restrict__ conv_b,
    const float* __restrict__ cib_w,   // D,CH
    const float* __restrict__ cib_b,
    const float* __restrict__ cpr1_w,  // D,2D  (wt = first half)
    const float* __restrict__ cpr2_w,  // D,D
    const float* __restrict__ cpr2_b,
    const float* __restrict__ Eb,      // B,D,SL (cpr1_b folded in)
    const float* __restrict__ cma_w,   // CH,D
    const float* __restrict__ cma_b) {
    int blk = blockIdx.x;
    int b = blk / (SST/S_TILE);
    int s0 = (blk % (SST/S_TILE)) * S_TILE;
    int tid = threadIdx.x;

    __shared__ float tin[CH][S_TILE+2];
    __shared__ float xc[CH][S_TILE+1];    // pad -> conflict-free strided reads
    __shared__ float cc[D_][S_TILE+1];
    __shared__ float Ac[D_][S_TILE+1];
    __shared__ float hl[D_][SL+1];        // pad 49: stride coprime with 32
    __shared__ float El[D_][SL+1];
    __shared__ float W2T[D_][D_];         // W2T[c][o]: lane-o-consecutive reads
    __shared__ float pm[D_][4];
    __shared__ float mcol[D_];

    for (int idx = tid; idx < D_*D_; idx += 256) {
        int o = idx >> 6, c = idx & 63;
        W2T[c][o] = cpr2_w[idx];
    }
    for (int idx = tid; idx < D_*SL; idx += 256) {
        int c = idx / SL, l = idx % SL;
        El[c][l] = Eb[(b*D_ + c)*SL + l];
    }
    for (int idx = tid; idx < CH*(S_TILE+2); idx += 256) {
        int c = idx / (S_TILE+2), j = idx % (S_TILE+2);
        int s = s0 + j - 2;
        tin[c][j] = (s >= 0) ? t_in[(b*CH + c)*SST + s] : 0.f;
    }
    __syncthreads();

    // xconv = relu(causal conv3): 224 threads = 112 o * 2 col-halves
    if (tid < 224) {
        int o = tid >> 1, half = tid & 1, j0 = half*4;
        float bo = conv_b[o];
        float acc0 = bo, acc1 = bo, acc2 = bo, acc3 = bo;
        const float* w = conv_w + o*CH*3;
        for (int c = 0; c < CH; ++c) {
            float w0 = w[c*3+0], w1 = w[c*3+1], w2 = w[c*3+2];
            float tv0 = tin[c][j0+0], tv1 = tin[c][j0+1], tv2 = tin[c][j0+2];
            float tv3 = tin[c][j0+3], tv4 = tin[c][j0+4], tv5 = tin[c][j0+5];
            acc0 += w0*tv0 + w1*tv1 + w2*tv2;
            acc1 += w0*tv1 + w1*tv2 + w2*tv3;
            acc2 += w0*tv2 + w1*tv3 + w2*tv4;
            acc3 += w0*tv3 + w1*tv4 + w2*tv5;
        }
        xc[o][j0+0] = fmaxf(acc0, 0.f);
        xc[o][j0+1] = fmaxf(acc1, 0.f);
        xc[o][j0+2] = fmaxf(acc2, 0.f);
        xc[o][j0+3] = fmaxf(acc3, 0.f);
    }
    __syncthreads();

    // c = cib_w @ xconv + cib_b : 256 threads = 64 d * 4 col-pairs
    {
        int d = tid & 63, jg = tid >> 6;
        int j0 = jg*2;
        float a0 = cib_b[d], a1 = a0;
        const float* w = cib_w + d*CH;
        for (int o = 0; o < CH; ++o) {
            float wv = w[o];
            a0 += wv * xc[o][j0];
            a1 += wv * xc[o][j0+1];
        }
        cc[d][j0] = a0; cc[d][j0+1] = a1;
    }
    __syncthreads();

    // A = wt @ c (bias folded into E)
    {
        int o = tid & 63, jg = tid >> 6;
        int j0 = jg*2;
        float a0 = 0.f, a1 = 0.f;
        const float* w = cpr1_w + o*(2*D_);
        for (int c = 0; c < D_; ++c) {
            float wv = w[c];
            a0 += wv * cc[c][j0];
            a1 += wv * cc[c][j0+1];
        }
        Ac[o][j0] = a0; Ac[o][j0+1] = a1;
    }
    __syncthreads();

    float b2v = cpr2_b[tid & 63];
    float cmab = (tid < CH) ? cma_b[tid] : 0.f;

    for (int j = 0; j < S_TILE; ++j) {
        // h = relu(A[:,j] + E)
        {
            int c = tid & 63, lg = tid >> 6;
            float a = Ac[c][j];
            #pragma unroll
            for (int i = 0; i < 12; ++i) {
                int l = lg*12 + i;
                hl[c][l] = fmaxf(a + El[c][l], 0.f);
            }
        }
        __syncthreads();
        // h2 = W2 @ h; running max over l (relu commutes with max)
        {
            int o = tid & 63, lg = tid >> 6;
            int l0 = lg*12;
            float acc[12];
            #pragma unroll
            for (int i = 0; i < 12; ++i) acc[i] = 0.f;
            for (int c = 0; c < D_; ++c) {
                float wv = W2T[c][o];
                #pragma unroll
                for (int i = 0; i < 12; ++i) acc[i] += wv * hl[c][l0+i];
            }
            float p = acc[0];
            #pragma unroll
            for (int i = 1; i < 12; ++i) p = fmaxf(p, acc[i]);
            pm[o][lg] = p;
        }
        __syncthreads();
        if (tid < D_) {
            float p = fmaxf(fmaxf(pm[tid][0], pm[tid][1]), fmaxf(pm[tid][2], pm[tid][3]));
            mcol[tid] = fmaxf(p + b2v, 0.f);
        }
        __syncthreads();
        // t_out = cma_w @ m + cma_b + xconv
        if (tid < CH) {
            float acc = cmab;
            const float* w = cma_w + tid*D_;
            #pragma unroll
            for (int d = 0; d < D_; ++d) acc += w[d]*mcol[d];
            t_out[(b*CH + tid)*SST + s0 + j] = acc + xc[tid][j];
        }
        __syncthreads();
    }
}

// ---------------- ccf = 1x1 conv ----------------
__global__ void ccf_kernel(const float* __restrict__ t_in,
                           const float* __restrict__ ccf_w,
                           const float* __restrict__ ccf_b,
                           float* __restrict__ ccf_out) {
    int bs = blockIdx.x;
    int b = bs / SST, s = bs % SST;
    int tid = threadIdx.x; // 128
    __shared__ float tcol[CH];
    if (tid < CH) tcol[tid] = t_in[(b*CH + tid)*SST + s];
    __syncthreads();
    if (tid < D_) {
        float acc = ccf_b[tid];
        const float* w = ccf_w + tid*CH;
        #pragma unroll
        for (int o = 0; o < CH; ++o) acc += w[o]*tcol[o];
        ccf_out[(b*D_ + tid)*SST + s] = acc;
    }
}

// ---------------- logits GEMM: out[b,s,v] = ccf[b,:,s]·emb[v,:] + fff_b[v] ----------------
__global__ __launch_bounds__(256) void logits_kernel(
    const float* __restrict__ ccf,   // B,D,SST
    const float* __restrict__ emb,   // VOCAB,D
    const float* __restrict__ fffb,
    float* __restrict__ out) {       // (B*SST),VOCAB
    int ntile = blockIdx.x % (VOCAB/64);
    int mtile = blockIdx.x / (VOCAB/64);
    int b = mtile >> 2;
    int s_base = (mtile & 3) << 6;
    int tid = threadIdx.x;
    __shared__ float As[D_][65];   // As[d][mm]
    __shared__ float Bs[D_][65];   // Bs[d][vv]
    {
        int d = tid >> 6, mm = tid & 63;
        #pragma unroll
        for (int i = 0; i < 16; ++i)
            As[d + i*4][mm] = ccf[(b*D_ + d + i*4)*SST + s_base + mm];
    }
    int v0 = ntile*64;
    {
        int vv = tid >> 6, d = tid & 63;
        #pragma unroll
        for (int i = 0; i < 16; ++i)
            Bs[d][vv + i*4] = emb[(size_t)(v0 + vv + i*4)*D_ + d];
    }
    __syncthreads();
    int tn = tid & 15, tm = tid >> 4;
    float acc[4][4];
    #pragma unroll
    for (int i = 0; i < 4; ++i)
        #pragma unroll
        for (int jj = 0; jj < 4; ++jj) acc[i][jj] = 0.f;
    for (int k = 0; k < D_; ++k) {
        float a[4], bb[4];
        #pragma unroll
        for (int i = 0; i < 4; ++i) a[i] = As[k][tm*4+i];
        #pragma unroll
        for (int jj = 0; jj < 4; ++jj) bb[jj] = Bs[k][tn*4+jj];
        #pragma unroll
        for (int i = 0; i < 4; ++i)
            #pragma unroll
            for (int jj = 0; jj < 4; ++jj) acc[i][jj] += a[i]*bb[jj];
    }
    float fb[4];
    #pragma unroll
    for (int jj = 0; jj < 4; ++jj) fb[jj] = fffb[v0 + tn*4 + jj];
    #pragma unroll
    for (int i = 0; i < 4; ++i) {
        int m = mtile*64 + tm*4 + i;
        float4 o4 = make_float4(acc[i][0]+fb[0], acc[i][1]+fb[1],
                                acc[i][2]+fb[2], acc[i][3]+fb[3]);
        *reinterpret_cast<float4*>(&out[(size_t)m*VOCAB + v0 + tn*4]) = o4;
    }
}

extern "C" void kernel_launch(void* const* d_in, const int* in_sizes, int n_in,
                              void* d_out, int out_size, void* d_ws, size_t ws_size,
                              hipStream_t stream) {
    const int*   x     = (const int*)d_in[0];
    const float* ees   = (const float*)d_in[1];
    const float* emb   = (const float*)d_in[2];
    const float* cl0_w = (const float*)d_in[3];
    const float* cl0_b = (const float*)d_in[4];
    const float* cl1_w = (const float*)d_in[5];
    const float* cl1_b = (const float*)d_in[6];
    const float* claa_w= (const float*)d_in[7];
    const float* claa_b= (const float*)d_in[8];
    const float* clfa_w= (const float*)d_in[9];
    const float* clfa_b= (const float*)d_in[10];
    const float* ccac_w= (const float*)d_in[11];
    const float* ccac_b= (const float*)d_in[12];
    const float* cib_w = (const float*)d_in[13];
    const float* cib_b = (const float*)d_in[14];
    const float* cpr1_w= (const float*)d_in[15];
    const float* cpr1_b= (const float*)d_in[16];
    const float* cpr2_w= (const float*)d_in[17];
    const float* cpr2_b= (const float*)d_in[18];
    const float* cma_w = (const float*)d_in[19];
    const float* cma_b = (const float*)d_in[20];
    const float* ccf_w = (const float*)d_in[21];
    const float* ccf_b = (const float*)d_in[22];
    const float* fff_b = (const float*)d_in[23];

    float* out = (float*)d_out;
    float* out_pre = out + OUT0_ELEMS;
    float* out_ccf = out_pre + OUT1_ELEMS;

    float* wsf = (float*)d_ws;
    float* t_a = wsf;
    float* t_b = wsf + T_ELEMS;
    float* Eb  = wsf + 2*T_ELEMS;

    gather_t0_kernel<<<B_*SST, 128, 0, stream>>>(x, emb, cl0_w, cl0_b, out_pre, t_a);
    e_kernel<<<B_*SL, 64, 0, stream>>>(ees, cpr1_w, cpr1_b, Eb);

    stage_kernel<<<B_*(SST/S_TILE), 256, 0, stream>>>(t_a, t_b, cl1_w, cl1_b,
        cib_w, cib_b, cpr1_w, cpr2_w, cpr2_b, Eb, cma_w, cma_b);
    stage_kernel<<<B_*(SST/S_TILE), 256, 0, stream>>>(t_b, t_a, claa_w, claa_b,
        cib_w, cib_b, cpr1_w, cpr2_w, cpr2_b, Eb, cma_w, cma_b);
    stage_kernel<<<B_*(SST/S_TILE), 256, 0, stream>>>(t_a, t_b, clfa_w, clfa_b,
        cib_w, cib_b, cpr1_w, cpr2_w, cpr2_b, Eb, cma_w, cma_b);
    stage_kernel<<<B_*(SST/S_TILE), 256, 0, stream>>>(t_b, t_a, ccac_w, ccac_b,
        cib_w, cib_b, cpr1_w, cpr2_w, cpr2_b, Eb, cma_w, cma_b);

    ccf_kernel<<<B_*SST, 128, 0, stream>>>(t_a, ccf_w, ccf_b, out_ccf);
    logits_kernel<<<(B_*SST/64)*(VOCAB/64), 256, 0, stream>>>(out_ccf, emb, fff_b, out);
}

// Round 2
// 392.909 us; speedup vs baseline: 1.3364x; 1.3364x over previous
//
#include <hip/hip_runtime.h>

#define B_ 16
#define SST 256
#define SL 48
#define VOCAB 16384
#define D_ 64
#define CH 112
#define S_TILE 8

#define T_ELEMS (B_*CH*SST)          // 458752
#define E_ELEMS (B_*D_*SL)           // 49152
#define OUT0_ELEMS ((size_t)B_*SST*VOCAB)
#define OUT1_ELEMS (B_*D_*SST)

typedef __attribute__((ext_vector_type(8))) short s8v;
typedef __attribute__((ext_vector_type(4))) float f32x4;

__device__ __forceinline__ unsigned short f2bf(float f) {
    union { float f; unsigned int u; } x; x.f = f;
    unsigned int r = x.u + 0x7fffu + ((x.u >> 16) & 1u);
    return (unsigned short)(r >> 16);
}
__device__ __forceinline__ float bf2f(unsigned short h) {
    union { unsigned int u; float f; } x; x.u = ((unsigned int)h) << 16;
    return x.f;
}

// ---------------- gather + cl0 (1x1 conv) ----------------
__global__ void gather_t0_kernel(const int* __restrict__ x,
                                 const float* __restrict__ emb,
                                 const float* __restrict__ cl0_w,
                                 const float* __restrict__ cl0_b,
                                 float* __restrict__ pre_d,   // B,D,SST
                                 float* __restrict__ t0) {    // B,CH,SST
    int bs = blockIdx.x;
    int b = bs / SST, s = bs % SST;
    int tid = threadIdx.x;
    __shared__ float ecol[D_];
    int v = x[b*SST + s];
    if (tid < D_) {
        float e = emb[v*D_ + tid];
        ecol[tid] = e;
        pre_d[(b*D_ + tid)*SST + s] = e;
    }
    __syncthreads();
    if (tid < CH) {
        float acc = cl0_b[tid];
        const float* w = cl0_w + tid*D_;
        #pragma unroll
        for (int d = 0; d < D_; ++d) acc += w[d]*ecol[d];
        t0[(b*CH + tid)*SST + s] = acc;
    }
}

// ---------------- E[b,o,l] = we @ ees + cpr1_b (stage-invariant) ----------------
__global__ void e_kernel(const float* __restrict__ ees,
                         const float* __restrict__ cpr1_w,
                         const float* __restrict__ cpr1_b,
                         float* __restrict__ Eb) {  // B,D,SL
    int bl = blockIdx.x;
    int b = bl / SL, l = bl % SL;
    int tid = threadIdx.x; // 64 threads
    __shared__ float ec[D_];
    ec[tid] = ees[(b*D_ + tid)*SL + l];
    __syncthreads();
    float acc = cpr1_b[tid];
    const float* w = cpr1_w + tid*(2*D_) + D_;
    #pragma unroll
    for (int c = 0; c < D_; ++c) acc += w[c]*ec[c];
    Eb[(b*D_ + tid)*SL + l] = acc;
}

// ---------------- emb -> bf16 hi/lo ----------------
__global__ void emb2bf_kernel(const float* __restrict__ emb,
                              unsigned short* __restrict__ hi,
                              unsigned short* __restrict__ lo) {
    int i = blockIdx.x*256 + threadIdx.x;   // per float4
    float4 v = reinterpret_cast<const float4*>(emb)[i];
    ushort4 h, l;
    h.x = f2bf(v.x); l.x = f2bf(v.x - bf2f(h.x));
    h.y = f2bf(v.y); l.y = f2bf(v.y - bf2f(h.y));
    h.z = f2bf(v.z); l.z = f2bf(v.z - bf2f(h.z));
    h.w = f2bf(v.w); l.w = f2bf(v.w - bf2f(h.w));
    reinterpret_cast<ushort4*>(hi)[i] = h;
    reinterpret_cast<ushort4*>(lo)[i] = l;
}

// ---------------- fused stage ----------------
__global__ __launch_bounds__(256) void stage_kernel(
    const float* __restrict__ t_in,
    float* __restrict__ t_out,
    const float* __restrict__ conv_w,  // CH,CH,3
    const float* __restrict__ conv_b,
    const float* __restrict__ cib_w,   // D,CH
    const float* __restrict__ cib_b,
    const float* __restrict__ cpr1_w,  // D,2D  (wt = first half)
    const float* __restrict__ cpr2_w,  // D,D
    const float* __restrict__ cpr2_b,
    const float* __restrict__ Eb,      // B,D,SL (cpr1_b folded in)
    const float* __restrict__ cma_w,   // CH,D
    const float* __restrict__ cma_b) {
    int blk = blockIdx.x;
    int b = blk / (SST/S_TILE);
    int s0 = (blk % (SST/S_TILE)) * S_TILE;
    int tid = threadIdx.x;

    __shared__ __align__(16) float tin[CH][12];   // j = 0..9 used
    __shared__ float xc[CH][S_TILE+1];
    __shared__ float cc[D_][S_TILE+1];
    __shared__ float Ac[D_][S_TILE+1];
    __shared__ __align__(16) float hl[D_][52];    // 52*4 = 208B rows, 16B aligned
    __shared__ __align__(16) float El[D_][52];
    __shared__ float W2T[D_][D_];                 // W2T[c][o]
    __shared__ float pm[D_][4];
    __shared__ float mcol[D_];

    for (int idx = tid; idx < D_*D_; idx += 256) {
        int o = idx >> 6, c = idx & 63;
        W2T[c][o] = cpr2_w[idx];
    }
    for (int idx = tid; idx < D_*SL; idx += 256) {
        int c = idx / SL, l = idx % SL;
        El[c][l] = Eb[(b*D_ + c)*SL + l];
    }
    for (int idx = tid; idx < CH*10; idx += 256) {
        int c = idx / 10, j = idx % 10;
        int s = s0 + j - 2;
        tin[c][j] = (s >= 0) ? t_in[(b*CH + c)*SST + s] : 0.f;
    }
    __syncthreads();

    // xconv = relu(causal conv3): 224 threads = 112 o * 2 col-halves
    if (tid < 224) {
        int o = tid >> 1, half = tid & 1, j0 = half*4;
        float bo = conv_b[o];
        float acc0 = bo, acc1 = bo, acc2 = bo, acc3 = bo;
        const float* w = conv_w + o*CH*3;
        for (int c = 0; c < CH; ++c) {
            float w0 = w[c*3+0], w1 = w[c*3+1], w2 = w[c*3+2];
            float4 t03 = *reinterpret_cast<const float4*>(&tin[c][j0]);
            float2 t45 = *reinterpret_cast<const float2*>(&tin[c][j0+4]);
            acc0 += w0*t03.x + w1*t03.y + w2*t03.z;
            acc1 += w0*t03.y + w1*t03.z + w2*t03.w;
            acc2 += w0*t03.z + w1*t03.w + w2*t45.x;
            acc3 += w0*t03.w + w1*t45.x + w2*t45.y;
        }
        xc[o][j0+0] = fmaxf(acc0, 0.f);
        xc[o][j0+1] = fmaxf(acc1, 0.f);
        xc[o][j0+2] = fmaxf(acc2, 0.f);
        xc[o][j0+3] = fmaxf(acc3, 0.f);
    }
    __syncthreads();

    // c = cib_w @ xconv + cib_b : 256 threads = 64 d * 4 col-pairs
    {
        int d = tid & 63, jg = tid >> 6;
        int j0 = jg*2;
        float a0 = cib_b[d], a1 = a0;
        const float* w = cib_w + d*CH;
        for (int o = 0; o < CH; ++o) {
            float wv = w[o];
            a0 += wv * xc[o][j0];
            a1 += wv * xc[o][j0+1];
        }
        cc[d][j0] = a0; cc[d][j0+1] = a1;
    }
    __syncthreads();

    // A = wt @ c (bias folded into E)
    {
        int o = tid & 63, jg = tid >> 6;
        int j0 = jg*2;
        float a0 = 0.f, a1 = 0.f;
        const float* w = cpr1_w + o*(2*D_);
        for (int c = 0; c < D_; ++c) {
            float wv = w[c];
            a0 += wv * cc[c][j0];
            a1 += wv * cc[c][j0+1];
        }
        Ac[o][j0] = a0; Ac[o][j0+1] = a1;
    }
    __syncthreads();

    float b2v = cpr2_b[tid & 63];
    float cmab = (tid < CH) ? cma_b[tid] : 0.f;

    for (int j = 0; j < S_TILE; ++j) {
        // h = relu(A[:,j] + E), float4 in/out
        {
            int c = tid & 63, lg = tid >> 6;
            int l0 = lg*12;
            float a = Ac[c][j];
            float4 e0 = *reinterpret_cast<const float4*>(&El[c][l0]);
            float4 e1 = *reinterpret_cast<const float4*>(&El[c][l0+4]);
            float4 e2 = *reinterpret_cast<const float4*>(&El[c][l0+8]);
            float4 h0, h1, h2;
            h0.x = fmaxf(a+e0.x, 0.f); h0.y = fmaxf(a+e0.y, 0.f);
            h0.z = fmaxf(a+e0.z, 0.f); h0.w = fmaxf(a+e0.w, 0.f);
            h1.x = fmaxf(a+e1.x, 0.f); h1.y = fmaxf(a+e1.y, 0.f);
            h1.z = fmaxf(a+e1.z, 0.f); h1.w = fmaxf(a+e1.w, 0.f);
            h2.x = fmaxf(a+e2.x, 0.f); h2.y = fmaxf(a+e2.y, 0.f);
            h2.z = fmaxf(a+e2.z, 0.f); h2.w = fmaxf(a+e2.w, 0.f);
            *reinterpret_cast<float4*>(&hl[c][l0])   = h0;
            *reinterpret_cast<float4*>(&hl[c][l0+4]) = h1;
            *reinterpret_cast<float4*>(&hl[c][l0+8]) = h2;
        }
        __syncthreads();
        // h2 = W2 @ h; running max over l (relu commutes with max)
        {
            int o = tid & 63, lg = tid >> 6;
            int l0 = lg*12;
            float4 a0 = {0.f,0.f,0.f,0.f}, a1 = a0, a2 = a0;
            #pragma unroll 4
            for (int c = 0; c < D_; ++c) {
                float wv = W2T[c][o];
                float4 h0 = *reinterpret_cast<const float4*>(&hl[c][l0]);
                float4 h1 = *reinterpret_cast<const float4*>(&hl[c][l0+4]);
                float4 h2 = *reinterpret_cast<const float4*>(&hl[c][l0+8]);
                a0.x += wv*h0.x; a0.y += wv*h0.y; a0.z += wv*h0.z; a0.w += wv*h0.w;
                a1.x += wv*h1.x; a1.y += wv*h1.y; a1.z += wv*h1.z; a1.w += wv*h1.w;
                a2.x += wv*h2.x; a2.y += wv*h2.y; a2.z += wv*h2.z; a2.w += wv*h2.w;
            }
            float p = fmaxf(fmaxf(fmaxf(a0.x,a0.y), fmaxf(a0.z,a0.w)),
                     fmaxf(fmaxf(fmaxf(a1.x,a1.y), fmaxf(a1.z,a1.w)),
                           fmaxf(fmaxf(a2.x,a2.y), fmaxf(a2.z,a2.w))));
            pm[o][lg] = p;
        }
        __syncthreads();
        if (tid < D_) {
            float p = fmaxf(fmaxf(pm[tid][0], pm[tid][1]), fmaxf(pm[tid][2], pm[tid][3]));
            mcol[tid] = fmaxf(p + b2v, 0.f);
        }
        __syncthreads();
        // t_out = cma_w @ m + cma_b + xconv
        if (tid < CH) {
            float acc = cmab;
            const float* w = cma_w + tid*D_;
            #pragma unroll
            for (int d = 0; d < D_; ++d) acc += w[d]*mcol[d];
            t_out[(b*CH + tid)*SST + s0 + j] = acc + xc[tid][j];
        }
        __syncthreads();
    }
}

// ---------------- ccf = 1x1 conv (+ bf16 hi/lo transpose for logits A) ----------------
__global__ void ccf_kernel(const float* __restrict__ t_in,
                           const float* __restrict__ ccf_w,
                           const float* __restrict__ ccf_b,
                           float* __restrict__ ccf_out,
                           unsigned short* __restrict__ Ahi,  // (B*SST) x D
                           unsigned short* __restrict__ Alo) {
    int bs = blockIdx.x;
    int b = bs / SST, s = bs % SST;
    int tid = threadIdx.x; // 128
    __shared__ float tcol[CH];
    if (tid < CH) tcol[tid] = t_in[(b*CH + tid)*SST + s];
    __syncthreads();
    if (tid < D_) {
        float acc = ccf_b[tid];
        const float* w = ccf_w + tid*CH;
        #pragma unroll
        for (int o = 0; o < CH; ++o) acc += w[o]*tcol[o];
        ccf_out[(b*D_ + tid)*SST + s] = acc;
        unsigned short hi = f2bf(acc);
        Ahi[(b*SST + s)*D_ + tid] = hi;
        Alo[(b*SST + s)*D_ + tid] = f2bf(acc - bf2f(hi));
    }
}

// ---------------- logits: MFMA bf16 hi/lo GEMM ----------------
// out[m, v] = A[m,:] . emb[v,:] + fff_b[v];  A = ccf^T (M x K), B = emb (N x K), K=64
__global__ __launch_bounds__(256) void logits_mfma_kernel(
    const unsigned short* __restrict__ Ahi,
    const unsigned short* __restrict__ Alo,
    const unsigned short* __restrict__ Bhi,
    const unsigned short* __restrict__ Blo,
    const float* __restrict__ fffb,
    float* __restrict__ out) {
    int ntile = blockIdx.x & 127;   // 128 n-tiles of 128 cols
    int mtile = blockIdx.x >> 7;    // 32 m-tiles of 128 rows
    int wid = threadIdx.x >> 6;
    int lane = threadIdx.x & 63;
    int wm = wid >> 1, wn = wid & 1;
    int m0 = mtile*128 + wm*64;
    int v0 = ntile*128 + wn*64;
    int row16 = lane & 15, kg = lane >> 4;

    const short* Ah = (const short*)Ahi;
    const short* Al = (const short*)Alo;
    const short* Bh = (const short*)Bhi;
    const short* Bl = (const short*)Blo;

    f32x4 acc[4][4];
    #pragma unroll
    for (int mi = 0; mi < 4; ++mi)
        #pragma unroll
        for (int ni = 0; ni < 4; ++ni)
            acc[mi][ni] = (f32x4){0.f, 0.f, 0.f, 0.f};

    #pragma unroll
    for (int kk = 0; kk < 2; ++kk) {
        int koff = kk*32 + kg*8;
        s8v ah[4], al[4], bh[4], bl[4];
        #pragma unroll
        for (int mi = 0; mi < 4; ++mi) {
            int r = (m0 + mi*16 + row16)*D_ + koff;
            ah[mi] = *reinterpret_cast<const s8v*>(Ah + r);
            al[mi] = *reinterpret_cast<const s8v*>(Al + r);
        }
        #pragma unroll
        for (int ni = 0; ni < 4; ++ni) {
            int r = (v0 + ni*16 + row16)*D_ + koff;
            bh[ni] = *reinterpret_cast<const s8v*>(Bh + r);
            bl[ni] = *reinterpret_cast<const s8v*>(Bl + r);
        }
        #pragma unroll
        for (int mi = 0; mi < 4; ++mi)
            #pragma unroll
            for (int ni = 0; ni < 4; ++ni) {
                acc[mi][ni] = __builtin_amdgcn_mfma_f32_16x16x32_bf16(ah[mi], bh[ni], acc[mi][ni], 0, 0, 0);
                acc[mi][ni] = __builtin_amdgcn_mfma_f32_16x16x32_bf16(ah[mi], bl[ni], acc[mi][ni], 0, 0, 0);
                acc[mi][ni] = __builtin_amdgcn_mfma_f32_16x16x32_bf16(al[mi], bh[ni], acc[mi][ni], 0, 0, 0);
            }
    }

    #pragma unroll
    for (int ni = 0; ni < 4; ++ni) {
        int v = v0 + ni*16 + row16;
        float fb = fffb[v];
        #pragma unroll
        for (int mi = 0; mi < 4; ++mi) {
            int mbase = m0 + mi*16 + kg*4;
            #pragma unroll
            for (int r = 0; r < 4; ++r) {
                __builtin_nontemporal_store(acc[mi][ni][r] + fb,
                    &out[(size_t)(mbase + r)*VOCAB + v]);
            }
        }
    }
}

extern "C" void kernel_launch(void* const* d_in, const int* in_sizes, int n_in,
                              void* d_out, int out_size, void* d_ws, size_t ws_size,
                              hipStream_t stream) {
    const int*   x     = (const int*)d_in[0];
    const float* ees   = (const float*)d_in[1];
    const float* emb   = (const float*)d_in[2];
    const float* cl0_w = (const float*)d_in[3];
    const float* cl0_b = (const float*)d_in[4];
    const float* cl1_w = (const float*)d_in[5];
    const float* cl1_b = (const float*)d_in[6];
    const float* claa_w= (const float*)d_in[7];
    const float* claa_b= (const float*)d_in[8];
    const float* clfa_w= (const float*)d_in[9];
    const float* clfa_b= (const float*)d_in[10];
    const float* ccac_w= (const float*)d_in[11];
    const float* ccac_b= (const float*)d_in[12];
    const float* cib_w = (const float*)d_in[13];
    const float* cib_b = (const float*)d_in[14];
    const float* cpr1_w= (const float*)d_in[15];
    const float* cpr1_b= (const float*)d_in[16];
    const float* cpr2_w= (const float*)d_in[17];
    const float* cpr2_b= (const float*)d_in[18];
    const float* cma_w = (const float*)d_in[19];
    const float* cma_b = (const float*)d_in[20];
    const float* ccf_w = (const float*)d_in[21];
    const float* ccf_b = (const float*)d_in[22];
    const float* fff_b = (const float*)d_in[23];

    float* out = (float*)d_out;
    float* out_pre = out + OUT0_ELEMS;
    float* out_ccf = out_pre + OUT1_ELEMS;

    float* wsf = (float*)d_ws;
    float* t_a = wsf;
    float* t_b = wsf + T_ELEMS;
    float* Eb  = wsf + 2*T_ELEMS;
    unsigned short* Ahi = (unsigned short*)(wsf + 2*T_ELEMS + E_ELEMS);
    unsigned short* Alo = Ahi + B_*SST*D_;
    unsigned short* EmbHi = Alo + B_*SST*D_;
    unsigned short* EmbLo = EmbHi + VOCAB*D_;

    gather_t0_kernel<<<B_*SST, 128, 0, stream>>>(x, emb, cl0_w, cl0_b, out_pre, t_a);
    e_kernel<<<B_*SL, 64, 0, stream>>>(ees, cpr1_w, cpr1_b, Eb);
    emb2bf_kernel<<<VOCAB*D_/4/256, 256, 0, stream>>>(emb, EmbHi, EmbLo);

    stage_kernel<<<B_*(SST/S_TILE), 256, 0, stream>>>(t_a, t_b, cl1_w, cl1_b,
        cib_w, cib_b, cpr1_w, cpr2_w, cpr2_b, Eb, cma_w, cma_b);
    stage_kernel<<<B_*(SST/S_TILE), 256, 0, stream>>>(t_b, t_a, claa_w, claa_b,
        cib_w, cib_b, cpr1_w, cpr2_w, cpr2_b, Eb, cma_w, cma_b);
    stage_kernel<<<B_*(SST/S_TILE), 256, 0, stream>>>(t_a, t_b, clfa_w, clfa_b,
        cib_w, cib_b, cpr1_w, cpr2_w, cpr2_b, Eb, cma_w, cma_b);
    stage_kernel<<<B_*(SST/S_TILE), 256, 0, stream>>>(t_b, t_a, ccac_w, ccac_b,
        cib_w, cib_b, cpr1_w, cpr2_w, cpr2_b, Eb, cma_w, cma_b);

    ccf_kernel<<<B_*SST, 128, 0, stream>>>(t_a, ccf_w, ccf_b, out_ccf, Ahi, Alo);
    logits_mfma_kernel<<<(B_*SST/128)*(VOCAB/128), 256, 0, stream>>>(
        Ahi, Alo, EmbHi, EmbLo, fff_b, out);
}

// Round 3
// 213.026 us; speedup vs baseline: 2.4648x; 1.8444x over previous
//
#include <hip/hip_runtime.h>

#define B_ 16
#define SST 256
#define SL 48
#define VOCAB 16384
#define D_ 64
#define CH 112

#define OUT0_ELEMS ((size_t)B_*SST*VOCAB)
#define OUT1_ELEMS (B_*D_*SST)

typedef __attribute__((ext_vector_type(8))) short s8v;
typedef __attribute__((ext_vector_type(4))) float f32x4;

__device__ __forceinline__ unsigned short f2bf_rne(float f) {
    union { float f; unsigned int u; } x; x.f = f;
    unsigned int r = x.u + 0x7fffu + ((x.u >> 16) & 1u);
    return (unsigned short)(r >> 16);
}
__device__ __forceinline__ float bf2f(unsigned short h) {
    union { unsigned int u; float f; } x; x.u = ((unsigned int)h) << 16;
    return x.f;
}
// truncation split: f = hi + lo exactly up to lo's bf16 truncation (~2^-16 rel total)
__device__ __forceinline__ void split1(float f, unsigned short* h, unsigned short* l) {
    unsigned u = __float_as_uint(f);
    *h = (unsigned short)(u >> 16);
    float lo = f - __uint_as_float(u & 0xffff0000u);
    *l = (unsigned short)(__float_as_uint(lo) >> 16);
}
// pack two floats -> {hi bf16 pair, lo bf16 pair}
__device__ __forceinline__ uint2 split_pack2(float f0, float f1) {
    unsigned u0 = __float_as_uint(f0), u1 = __float_as_uint(f1);
    unsigned hp = (u0 >> 16) | (u1 & 0xffff0000u);
    float l0 = f0 - __uint_as_float(u0 & 0xffff0000u);
    float l1 = f1 - __uint_as_float(u1 & 0xffff0000u);
    unsigned lp = (__float_as_uint(l0) >> 16) | (__float_as_uint(l1) & 0xffff0000u);
    return make_uint2(hp, lp);
}

// ---------------- gather + cl0 -> t0 (bf16 hi/lo, [b][s][c]) ----------------
__global__ void gather_t0_kernel(const int* __restrict__ x,
                                 const float* __restrict__ emb,
                                 const float* __restrict__ cl0_w,
                                 const float* __restrict__ cl0_b,
                                 float* __restrict__ pre_d,          // B,D,SST
                                 unsigned short* __restrict__ th,    // B*SST, CH
                                 unsigned short* __restrict__ tl) {
    int bs = blockIdx.x;
    int b = bs / SST, s = bs % SST;
    int tid = threadIdx.x;
    __shared__ float ecol[D_];
    int v = x[b*SST + s];
    if (tid < D_) {
        float e = emb[v*D_ + tid];
        ecol[tid] = e;
        pre_d[(b*D_ + tid)*SST + s] = e;
    }
    __syncthreads();
    if (tid < CH) {
        float acc = cl0_b[tid];
        const float* w = cl0_w + tid*D_;
        #pragma unroll
        for (int d = 0; d < D_; ++d) acc += w[d]*ecol[d];
        unsigned short h, l; split1(acc, &h, &l);
        th[(b*SST + s)*CH + tid] = h;
        tl[(b*SST + s)*CH + tid] = l;
    }
}

// ---- E[b,l,o] = we@ees + cpr1_b + wt@cib_b  (all per-o constants folded) ----
__global__ void e_kernel(const float* __restrict__ ees,
                         const float* __restrict__ cpr1_w,  // [64][128]
                         const float* __restrict__ cpr1_b,
                         const float* __restrict__ cib_b,   // [64]
                         float* __restrict__ Eb) {          // B,SL,64
    int bl = blockIdx.x;
    int b = bl / SL, l = bl % SL;
    int tid = threadIdx.x; // 64
    __shared__ float ec[D_];
    ec[tid] = ees[(b*D_ + tid)*SL + l];
    __syncthreads();
    const float* wrow = cpr1_w + tid*(2*D_);
    float acc = cpr1_b[tid];
    #pragma unroll
    for (int k = 0; k < D_; ++k) acc += wrow[k]*cib_b[k];      // bias_comb
    #pragma unroll
    for (int c = 0; c < D_; ++c) acc += wrow[D_ + c]*ec[c];    // we @ ees
    Eb[(b*SL + l)*D_ + tid] = acc;
}

// ---------------- emb -> bf16 hi/lo (for logits B) ----------------
__global__ void emb2bf_kernel(const float* __restrict__ emb,
                              unsigned short* __restrict__ hi,
                              unsigned short* __restrict__ lo) {
    int i = blockIdx.x*256 + threadIdx.x;   // per float4
    float4 v = reinterpret_cast<const float4*>(emb)[i];
    ushort4 h, l;
    split1(v.x, &h.x, &l.x);
    split1(v.y, &h.y, &l.y);
    split1(v.z, &h.z, &l.z);
    split1(v.w, &h.w, &l.w);
    reinterpret_cast<ushort4*>(hi)[i] = h;
    reinterpret_cast<ushort4*>(lo)[i] = l;
}

// ---------------- conv weight prep: Wc[st][k][o:128][c:128] hi/lo ----------------
__global__ void conv_prep_kernel(const float* __restrict__ w0, const float* __restrict__ w1,
                                 const float* __restrict__ w2, const float* __restrict__ w3,
                                 unsigned short* __restrict__ Wch, unsigned short* __restrict__ Wcl) {
    int gid = blockIdx.x*256 + threadIdx.x;   // 4*3*128*128
    int c = gid & 127;
    int o = (gid >> 7) & 127;
    int kst = gid >> 14;          // st*3 + k
    int k = kst % 3, st = kst / 3;
    const float* w = (st == 0) ? w0 : (st == 1) ? w1 : (st == 2) ? w2 : w3;
    float v = (o < CH && c < CH) ? w[o*CH*3 + c*3 + k] : 0.f;
    unsigned short h, l; split1(v, &h, &l);
    Wch[gid] = h; Wcl[gid] = l;
}

// ---------------- shared weight prep: Wcomb, W2, cma ----------------
__global__ void shared_prep_kernel(const float* __restrict__ cpr1_w,
                                   const float* __restrict__ cib_w,
                                   const float* __restrict__ cpr2_w,
                                   const float* __restrict__ cma_w,
                                   unsigned short* __restrict__ Wcomb_h, unsigned short* __restrict__ Wcomb_l,
                                   unsigned short* __restrict__ W2h, unsigned short* __restrict__ W2l,
                                   unsigned short* __restrict__ cmah, unsigned short* __restrict__ cmal) {
    int gid = blockIdx.x*256 + threadIdx.x;
    if (gid < 8192) {               // Wcomb[o:64][c:128] = wt @ cib_w
        int o = gid >> 7, c = gid & 127;
        float v = 0.f;
        if (c < CH) {
            const float* wrow = cpr1_w + o*(2*D_);
            #pragma unroll
            for (int k = 0; k < D_; ++k) v += wrow[k]*cib_w[k*CH + c];
        }
        unsigned short h, l; split1(v, &h, &l);
        Wcomb_h[gid] = h; Wcomb_l[gid] = l;
    } else if (gid < 12288) {       // W2[o:64][c:64]
        int idx = gid - 8192;
        unsigned short h, l; split1(cpr2_w[idx], &h, &l);
        W2h[idx] = h; W2l[idx] = l;
    } else if (gid < 20480) {       // cma[o:128][c:64]
        int idx = gid - 12288;
        int o = idx >> 6;
        float v = (o < CH) ? cma_w[idx] : 0.f;
        unsigned short h, l; split1(v, &h, &l);
        cmah[idx] = h; cmal[idx] = l;
    }
}

// ---------------- fused stage (all-MFMA) ----------------
// block: 512 threads (8 waves), one (b, 16-wide s-tile); grid 256
__global__ __launch_bounds__(512) void stage_kernel(
    const unsigned short* __restrict__ th, const unsigned short* __restrict__ tl,
    unsigned short* __restrict__ oh, unsigned short* __restrict__ ol,
    const unsigned short* __restrict__ Wch, const unsigned short* __restrict__ Wcl, // stage-offset
    const float* __restrict__ conv_b,
    const unsigned short* __restrict__ Wcomb_h, const unsigned short* __restrict__ Wcomb_l,
    const unsigned short* __restrict__ W2h, const unsigned short* __restrict__ W2l,
    const float* __restrict__ cpr2_b,
    const unsigned short* __restrict__ cmah, const unsigned short* __restrict__ cmal,
    const float* __restrict__ cma_b,
    const float* __restrict__ Eb) {
    int b = blockIdx.x >> 4;
    int s0 = (blockIdx.x & 15) << 4;
    int tid = threadIdx.x;
    int w = tid >> 6, lane = tid & 63, n = lane & 15, kg = lane >> 4;

    __shared__ unsigned short Tt_h[18*136], Tt_l[18*136];   // [row s0-2+r][c pad136]
    __shared__ unsigned short Xt_h[16*136], Xt_l[16*136];   // xconv^T [s][o pad136]
    __shared__ float El[48*68];                             // [l][c pad68]
    __shared__ float AcT[16*68];                            // [s][c pad68]
    __shared__ unsigned short W2hs[64*72], W2ls[64*72];     // [o][c pad72]
    __shared__ unsigned short Mm_h[16*72], Mm_l[16*72];     // [s][o pad72]

    const int tbase = b*SST*CH;
    for (int idx = tid; idx < 18*CH; idx += 512) {
        int r = idx / CH, c = idx % CH;
        int s = s0 - 2 + r;
        Tt_h[r*136 + c] = (s >= 0) ? th[tbase + s*CH + c] : 0;
        Tt_l[r*136 + c] = (s >= 0) ? tl[tbase + s*CH + c] : 0;
    }
    for (int idx = tid; idx < 18*16; idx += 512) {           // zero K-pad cols 112..127
        int r = idx >> 4, c = CH + (idx & 15);
        Tt_h[r*136 + c] = 0; Tt_l[r*136 + c] = 0;
    }
    for (int idx = tid; idx < 48*64; idx += 512) {
        int l = idx >> 6, c = idx & 63;
        El[l*68 + c] = Eb[(b*SL + l)*64 + c];
    }
    for (int idx = tid; idx < 4096; idx += 512) {
        int o = idx >> 6, c = idx & 63;
        W2hs[o*72 + c] = W2h[idx];
        W2ls[o*72 + c] = W2l[idx];
    }
    __syncthreads();

    // ---- P1: xconv = relu(conv3) ; wave w -> o-tile w (o = w*16.. pad to 128) ----
    f32x4 xcv = {0.f, 0.f, 0.f, 0.f};
    {
        #pragma unroll
        for (int k = 0; k < 3; ++k) {
            #pragma unroll
            for (int kt = 0; kt < 4; ++kt) {
                int cc = kt*32 + kg*8;
                s8v bh = *(const s8v*)&Tt_h[(n + k)*136 + cc];
                s8v bl = *(const s8v*)&Tt_l[(n + k)*136 + cc];
                int ai = (k*128 + w*16 + n)*128 + cc;
                s8v ah = *(const s8v*)&Wch[ai];
                s8v al = *(const s8v*)&Wcl[ai];
                xcv = __builtin_amdgcn_mfma_f32_16x16x32_bf16(ah, bh, xcv, 0, 0, 0);
                xcv = __builtin_amdgcn_mfma_f32_16x16x32_bf16(ah, bl, xcv, 0, 0, 0);
                xcv = __builtin_amdgcn_mfma_f32_16x16x32_bf16(al, bh, xcv, 0, 0, 0);
            }
        }
        int ob = w*16 + kg*4;
        #pragma unroll
        for (int r = 0; r < 4; ++r) {
            float cb = (ob + r < CH) ? conv_b[ob + r] : 0.f;
            xcv[r] = fmaxf(xcv[r] + cb, 0.f);
        }
        uint2 p01 = split_pack2(xcv[0], xcv[1]);
        uint2 p23 = split_pack2(xcv[2], xcv[3]);
        *(uint2*)&Xt_h[n*136 + ob] = make_uint2(p01.x, p23.x);
        *(uint2*)&Xt_l[n*136 + ob] = make_uint2(p01.y, p23.y);
    }
    __syncthreads();

    // ---- P2: Ac = Wcomb @ xconv (bias folded into El); waves 0..3 ----
    if (w < 4) {
        f32x4 acc = {0.f, 0.f, 0.f, 0.f};
        #pragma unroll
        for (int kt = 0; kt < 4; ++kt) {
            int cc = kt*32 + kg*8;
            int ai = (w*16 + n)*128 + cc;
            s8v ah = *(const s8v*)&Wcomb_h[ai];
            s8v al = *(const s8v*)&Wcomb_l[ai];
            s8v bh = *(const s8v*)&Xt_h[n*136 + cc];
            s8v bl = *(const s8v*)&Xt_l[n*136 + cc];
            acc = __builtin_amdgcn_mfma_f32_16x16x32_bf16(ah, bh, acc, 0, 0, 0);
            acc = __builtin_amdgcn_mfma_f32_16x16x32_bf16(ah, bl, acc, 0, 0, 0);
            acc = __builtin_amdgcn_mfma_f32_16x16x32_bf16(al, bh, acc, 0, 0, 0);
        }
        *(float4*)&AcT[n*68 + w*16 + kg*4] = make_float4(acc[0], acc[1], acc[2], acc[3]);
    }
    __syncthreads();

    // ---- P3: per s: h = relu(Ac + El); h2 = W2 @ h; m = relu(max_l h2 + b2) ----
    s8v a2h[4][2], a2l[4][2];
    #pragma unroll
    for (int mt = 0; mt < 4; ++mt)
        #pragma unroll
        for (int kt = 0; kt < 2; ++kt) {
            int ai = (mt*16 + n)*72 + kt*32 + kg*8;
            a2h[mt][kt] = *(const s8v*)&W2hs[ai];
            a2l[mt][kt] = *(const s8v*)&W2ls[ai];
        }
    int o_lane = ((n >> 2) << 4) + (kg << 2) + (n & 3);
    float b2_lane = cpr2_b[o_lane];

    #pragma unroll
    for (int si = 0; si < 2; ++si) {
        int s = w*2 + si;
        f32x4 acc[4][3];
        #pragma unroll
        for (int mt = 0; mt < 4; ++mt)
            #pragma unroll
            for (int lt = 0; lt < 3; ++lt)
                acc[mt][lt] = (f32x4){0.f, 0.f, 0.f, 0.f};

        #pragma unroll
        for (int kt = 0; kt < 2; ++kt) {
            int cc = kt*32 + kg*8;
            float4 aA = *(const float4*)&AcT[s*68 + cc];
            float4 aB = *(const float4*)&AcT[s*68 + cc + 4];
            #pragma unroll
            for (int lt = 0; lt < 3; ++lt) {
                const float* ep = &El[(lt*16 + n)*68 + cc];
                float4 e0 = *(const float4*)ep;
                float4 e1 = *(const float4*)(ep + 4);
                float h0 = fmaxf(aA.x + e0.x, 0.f);
                float h1 = fmaxf(aA.y + e0.y, 0.f);
                float h2 = fmaxf(aA.z + e0.z, 0.f);
                float h3 = fmaxf(aA.w + e0.w, 0.f);
                float h4 = fmaxf(aB.x + e1.x, 0.f);
                float h5 = fmaxf(aB.y + e1.y, 0.f);
                float h6 = fmaxf(aB.z + e1.z, 0.f);
                float h7 = fmaxf(aB.w + e1.w, 0.f);
                uint2 q0 = split_pack2(h0, h1);
                uint2 q1 = split_pack2(h2, h3);
                uint2 q2 = split_pack2(h4, h5);
                uint2 q3 = split_pack2(h6, h7);
                union { unsigned u[4]; s8v v; } Bh, Bl;
                Bh.u[0] = q0.x; Bh.u[1] = q1.x; Bh.u[2] = q2.x; Bh.u[3] = q3.x;
                Bl.u[0] = q0.y; Bl.u[1] = q1.y; Bl.u[2] = q2.y; Bl.u[3] = q3.y;
                #pragma unroll
                for (int mt = 0; mt < 4; ++mt) {
                    acc[mt][lt] = __builtin_amdgcn_mfma_f32_16x16x32_bf16(a2h[mt][kt], Bh.v, acc[mt][lt], 0, 0, 0);
                    acc[mt][lt] = __builtin_amdgcn_mfma_f32_16x16x32_bf16(a2h[mt][kt], Bl.v, acc[mt][lt], 0, 0, 0);
                    acc[mt][lt] = __builtin_amdgcn_mfma_f32_16x16x32_bf16(a2l[mt][kt], Bh.v, acc[mt][lt], 0, 0, 0);
                }
            }
        }
        // max over l: combine lt, then 16-lane butterfly
        float mx[16];
        #pragma unroll
        for (int mt = 0; mt < 4; ++mt)
            #pragma unroll
            for (int r = 0; r < 4; ++r)
                mx[mt*4 + r] = fmaxf(fmaxf(acc[mt][0][r], acc[mt][1][r]), acc[mt][2][r]);
        #pragma unroll
        for (int step = 0; step < 4; ++step) {
            int msk = 1 << step;
            #pragma unroll
            for (int i = 0; i < 16; ++i)
                mx[i] = fmaxf(mx[i], __shfl_xor(mx[i], msk));
        }
        float sel = mx[0];
        #pragma unroll
        for (int i = 1; i < 16; ++i)
            sel = (n == i) ? mx[i] : sel;
        float mval = fmaxf(sel + b2_lane, 0.f);
        unsigned short mh, ml; split1(mval, &mh, &ml);
        Mm_h[s*72 + o_lane] = mh;
        Mm_l[s*72 + o_lane] = ml;
    }
    __syncthreads();

    // ---- P4: t_out = cma @ m + cma_b + xconv ----
    {
        f32x4 acc = {0.f, 0.f, 0.f, 0.f};
        #pragma unroll
        for (int kt = 0; kt < 2; ++kt) {
            int cc = kt*32 + kg*8;
            int ai = (w*16 + n)*64 + cc;
            s8v ah = *(const s8v*)&cmah[ai];
            s8v al = *(const s8v*)&cmal[ai];
            s8v bh = *(const s8v*)&Mm_h[n*72 + cc];
            s8v bl = *(const s8v*)&Mm_l[n*72 + cc];
            acc = __builtin_amdgcn_mfma_f32_16x16x32_bf16(ah, bh, acc, 0, 0, 0);
            acc = __builtin_amdgcn_mfma_f32_16x16x32_bf16(ah, bl, acc, 0, 0, 0);
            acc = __builtin_amdgcn_mfma_f32_16x16x32_bf16(al, bh, acc, 0, 0, 0);
        }
        int ob = w*16 + kg*4;
        if (ob < CH) {
            float v0 = acc[0] + cma_b[ob + 0] + xcv[0];
            float v1 = acc[1] + cma_b[ob + 1] + xcv[1];
            float v2 = acc[2] + cma_b[ob + 2] + xcv[2];
            float v3 = acc[3] + cma_b[ob + 3] + xcv[3];
            uint2 p01 = split_pack2(v0, v1);
            uint2 p23 = split_pack2(v2, v3);
            int go = tbase + (s0 + n)*CH + ob;
            *(uint2*)&oh[go] = make_uint2(p01.x, p23.x);
            *(uint2*)&ol[go] = make_uint2(p01.y, p23.y);
        }
    }
}

// ---------------- ccf = 1x1 conv (reads t hi/lo) ----------------
__global__ void ccf_kernel(const unsigned short* __restrict__ th,
                           const unsigned short* __restrict__ tl,
                           const float* __restrict__ ccf_w,
                           const float* __restrict__ ccf_b,
                           float* __restrict__ ccf_out,
                           unsigned short* __restrict__ Ahi,  // (B*SST) x D
                           unsigned short* __restrict__ Alo) {
    int bs = blockIdx.x;
    int b = bs / SST, s = bs % SST;
    int tid = threadIdx.x; // 128
    __shared__ float tcol[CH];
    if (tid < CH) {
        int gi = (b*SST + s)*CH + tid;
        tcol[tid] = bf2f(th[gi]) + bf2f(tl[gi]);
    }
    __syncthreads();
    if (tid < D_) {
        float acc = ccf_b[tid];
        const float* w = ccf_w + tid*CH;
        #pragma unroll
        for (int o = 0; o < CH; ++o) acc += w[o]*tcol[o];
        ccf_out[(b*D_ + tid)*SST + s] = acc;
        unsigned short hi = f2bf_rne(acc);
        Ahi[(b*SST + s)*D_ + tid] = hi;
        Alo[(b*SST + s)*D_ + tid] = f2bf_rne(acc - bf2f(hi));
    }
}

// ---------------- logits: MFMA bf16 hi/lo GEMM ----------------
__global__ __launch_bounds__(256) void logits_mfma_kernel(
    const unsigned short* __restrict__ Ahi,
    const unsigned short* __restrict__ Alo,
    const unsigned short* __restrict__ Bhi,
    const unsigned short* __restrict__ Blo,
    const float* __restrict__ fffb,
    float* __restrict__ out) {
    int ntile = blockIdx.x & 127;
    int mtile = blockIdx.x >> 7;
    int wid = threadIdx.x >> 6;
    int lane = threadIdx.x & 63;
    int wm = wid >> 1, wn = wid & 1;
    int m0 = mtile*128 + wm*64;
    int v0 = ntile*128 + wn*64;
    int row16 = lane & 15, kg = lane >> 4;

    const short* Ah = (const short*)Ahi;
    const short* Al = (const short*)Alo;
    const short* Bh = (const short*)Bhi;
    const short* Bl = (const short*)Blo;

    f32x4 acc[4][4];
    #pragma unroll
    for (int mi = 0; mi < 4; ++mi)
        #pragma unroll
        for (int ni = 0; ni < 4; ++ni)
            acc[mi][ni] = (f32x4){0.f, 0.f, 0.f, 0.f};

    #pragma unroll
    for (int kk = 0; kk < 2; ++kk) {
        int koff = kk*32 + kg*8;
        s8v ah[4], al[4], bh[4], bl[4];
        #pragma unroll
        for (int mi = 0; mi < 4; ++mi) {
            int r = (m0 + mi*16 + row16)*D_ + koff;
            ah[mi] = *reinterpret_cast<const s8v*>(Ah + r);
            al[mi] = *reinterpret_cast<const s8v*>(Al + r);
        }
        #pragma unroll
        for (int ni = 0; ni < 4; ++ni) {
            int r = (v0 + ni*16 + row16)*D_ + koff;
            bh[ni] = *reinterpret_cast<const s8v*>(Bh + r);
            bl[ni] = *reinterpret_cast<const s8v*>(Bl + r);
        }
        #pragma unroll
        for (int mi = 0; mi < 4; ++mi)
            #pragma unroll
            for (int ni = 0; ni < 4; ++ni) {
                acc[mi][ni] = __builtin_amdgcn_mfma_f32_16x16x32_bf16(ah[mi], bh[ni], acc[mi][ni], 0, 0, 0);
                acc[mi][ni] = __builtin_amdgcn_mfma_f32_16x16x32_bf16(ah[mi], bl[ni], acc[mi][ni], 0, 0, 0);
                acc[mi][ni] = __builtin_amdgcn_mfma_f32_16x16x32_bf16(al[mi], bh[ni], acc[mi][ni], 0, 0, 0);
            }
    }

    #pragma unroll
    for (int ni = 0; ni < 4; ++ni) {
        int v = v0 + ni*16 + row16;
        float fb = fffb[v];
        #pragma unroll
        for (int mi = 0; mi < 4; ++mi) {
            int mbase = m0 + mi*16 + kg*4;
            #pragma unroll
            for (int r = 0; r < 4; ++r) {
                __builtin_nontemporal_store(acc[mi][ni][r] + fb,
                    &out[(size_t)(mbase + r)*VOCAB + v]);
            }
        }
    }
}

extern "C" void kernel_launch(void* const* d_in, const int* in_sizes, int n_in,
                              void* d_out, int out_size, void* d_ws, size_t ws_size,
                              hipStream_t stream) {
    const int*   x     = (const int*)d_in[0];
    const float* ees   = (const float*)d_in[1];
    const float* emb   = (const float*)d_in[2];
    const float* cl0_w = (const float*)d_in[3];
    const float* cl0_b = (const float*)d_in[4];
    const float* cl1_w = (const float*)d_in[5];
    const float* cl1_b = (const float*)d_in[6];
    const float* claa_w= (const float*)d_in[7];
    const float* claa_b= (const float*)d_in[8];
    const float* clfa_w= (const float*)d_in[9];
    const float* clfa_b= (const float*)d_in[10];
    const float* ccac_w= (const float*)d_in[11];
    const float* ccac_b= (const float*)d_in[12];
    const float* cib_w = (const float*)d_in[13];
    const float* cib_b = (const float*)d_in[14];
    const float* cpr1_w= (const float*)d_in[15];
    const float* cpr1_b= (const float*)d_in[16];
    const float* cpr2_w= (const float*)d_in[17];
    const float* cpr2_b= (const float*)d_in[18];
    const float* cma_w = (const float*)d_in[19];
    const float* cma_b = (const float*)d_in[20];
    const float* ccf_w = (const float*)d_in[21];
    const float* ccf_b = (const float*)d_in[22];
    const float* fff_b = (const float*)d_in[23];

    float* out = (float*)d_out;
    float* out_pre = out + OUT0_ELEMS;
    float* out_ccf = out_pre + OUT1_ELEMS;

    // logits inputs live in d_ws (read while logits writes out0)
    unsigned short* EmbHi = (unsigned short*)d_ws;
    unsigned short* EmbLo = EmbHi + VOCAB*D_;
    unsigned short* Ahi   = EmbLo + VOCAB*D_;
    unsigned short* Alo   = Ahi + B_*SST*D_;

    // everything consumed before logits -> scratch inside out0 (rewritten last)
    char* sc = (char*)d_out + (size_t)16*1024*1024;
    unsigned short* t_a_h = (unsigned short*)sc;              sc += B_*SST*CH*2;
    unsigned short* t_a_l = (unsigned short*)sc;              sc += B_*SST*CH*2;
    unsigned short* t_b_h = (unsigned short*)sc;              sc += B_*SST*CH*2;
    unsigned short* t_b_l = (unsigned short*)sc;              sc += B_*SST*CH*2;
    float*          Eb    = (float*)sc;                       sc += B_*SL*D_*4;
    unsigned short* Wch   = (unsigned short*)sc;              sc += 4*3*128*128*2;
    unsigned short* Wcl   = (unsigned short*)sc;              sc += 4*3*128*128*2;
    unsigned short* Wcombh= (unsigned short*)sc;              sc += 64*128*2;
    unsigned short* Wcombl= (unsigned short*)sc;              sc += 64*128*2;
    unsigned short* W2h   = (unsigned short*)sc;              sc += 64*64*2;
    unsigned short* W2l   = (unsigned short*)sc;              sc += 64*64*2;
    unsigned short* cmah  = (unsigned short*)sc;              sc += 128*64*2;
    unsigned short* cmal  = (unsigned short*)sc;              sc += 128*64*2;

    // ---- prep ----
    conv_prep_kernel<<<768, 256, 0, stream>>>(cl1_w, claa_w, clfa_w, ccac_w, Wch, Wcl);
    shared_prep_kernel<<<80, 256, 0, stream>>>(cpr1_w, cib_w, cpr2_w, cma_w,
                                               Wcombh, Wcombl, W2h, W2l, cmah, cmal);
    emb2bf_kernel<<<VOCAB*D_/4/256, 256, 0, stream>>>(emb, EmbHi, EmbLo);
    gather_t0_kernel<<<B_*SST, 128, 0, stream>>>(x, emb, cl0_w, cl0_b, out_pre, t_a_h, t_a_l);
    e_kernel<<<B_*SL, 64, 0, stream>>>(ees, cpr1_w, cpr1_b, cib_b, Eb);

    // ---- 4 stages (ping-pong) ----
    const int WCS = 3*128*128;
    stage_kernel<<<256, 512, 0, stream>>>(t_a_h, t_a_l, t_b_h, t_b_l,
        Wch + 0*WCS, Wcl + 0*WCS, cl1_b, Wcombh, Wcombl, W2h, W2l, cpr2_b, cmah, cmal, cma_b, Eb);
    stage_kernel<<<256, 512, 0, stream>>>(t_b_h, t_b_l, t_a_h, t_a_l,
        Wch + 1*WCS, Wcl + 1*WCS, claa_b, Wcombh, Wcombl, W2h, W2l, cpr2_b, cmah, cmal, cma_b, Eb);
    stage_kernel<<<256, 512, 0, stream>>>(t_a_h, t_a_l, t_b_h, t_b_l,
        Wch + 2*WCS, Wcl + 2*WCS, clfa_b, Wcombh, Wcombl, W2h, W2l, cpr2_b, cmah, cmal, cma_b, Eb);
    stage_kernel<<<256, 512, 0, stream>>>(t_b_h, t_b_l, t_a_h, t_a_l,
        Wch + 3*WCS, Wcl + 3*WCS, ccac_b, Wcombh, Wcombl, W2h, W2l, cpr2_b, cmah, cmal, cma_b, Eb);

    // ---- epilogue ----
    ccf_kernel<<<B_*SST, 128, 0, stream>>>(t_a_h, t_a_l, ccf_w, ccf_b, out_ccf, Ahi, Alo);
    logits_mfma_kernel<<<(B_*SST/128)*(VOCAB/128), 256, 0, stream>>>(
        Ahi, Alo, EmbHi, EmbLo, fff_b, out);
}

// Round 4
// 203.906 us; speedup vs baseline: 2.5751x; 1.0447x over previous
//
#include <hip/hip_runtime.h>

#define B_ 16
#define SST 256
#define SL 48
#define VOCAB 16384
#define D_ 64
#define CH 112

#define OUT0_ELEMS ((size_t)B_*SST*VOCAB)
#define OUT1_ELEMS (B_*D_*SST)

typedef __attribute__((ext_vector_type(8))) short s8v;
typedef __attribute__((ext_vector_type(4))) float f32x4;

#define MFMA(a,b,c) __builtin_amdgcn_mfma_f32_16x16x32_bf16(a, b, c, 0, 0, 0)

__device__ __forceinline__ void split1(float f, unsigned short* h, unsigned short* l) {
    unsigned u = __float_as_uint(f);
    *h = (unsigned short)(u >> 16);
    float lo = f - __uint_as_float(u & 0xffff0000u);
    *l = (unsigned short)(__float_as_uint(lo) >> 16);
}
__device__ __forceinline__ uint2 split_pack2(float f0, float f1) {
    unsigned u0 = __float_as_uint(f0), u1 = __float_as_uint(f1);
    unsigned hp = (u0 >> 16) | (u1 & 0xffff0000u);
    float l0 = f0 - __uint_as_float(u0 & 0xffff0000u);
    float l1 = f1 - __uint_as_float(u1 & 0xffff0000u);
    unsigned lp = (__float_as_uint(l0) >> 16) | (__float_as_uint(l1) & 0xffff0000u);
    return make_uint2(hp, lp);
}

// ---------------- E[b,l,o] = we@ees + cpr1_b + wt@cib_b ----------------
__global__ void e_kernel(const float* __restrict__ ees,
                         const float* __restrict__ cpr1_w,
                         const float* __restrict__ cpr1_b,
                         const float* __restrict__ cib_b,
                         float* __restrict__ Eb) {          // B,SL,64
    int bl = blockIdx.x;
    int b = bl / SL, l = bl % SL;
    int tid = threadIdx.x; // 64
    __shared__ float ec[D_];
    ec[tid] = ees[(b*D_ + tid)*SL + l];
    __syncthreads();
    const float* wrow = cpr1_w + tid*(2*D_);
    float acc = cpr1_b[tid];
    #pragma unroll
    for (int k = 0; k < D_; ++k) acc += wrow[k]*cib_b[k];
    #pragma unroll
    for (int c = 0; c < D_; ++c) acc += wrow[D_ + c]*ec[c];
    Eb[(b*SL + l)*D_ + tid] = acc;
}

// ---------------- emb -> bf16 hi/lo ----------------
__global__ void emb2bf_kernel(const float* __restrict__ emb,
                              unsigned short* __restrict__ hi,
                              unsigned short* __restrict__ lo) {
    int i = blockIdx.x*256 + threadIdx.x;
    float4 v = reinterpret_cast<const float4*>(emb)[i];
    ushort4 h, l;
    split1(v.x, &h.x, &l.x);
    split1(v.y, &h.y, &l.y);
    split1(v.z, &h.z, &l.z);
    split1(v.w, &h.w, &l.w);
    reinterpret_cast<ushort4*>(hi)[i] = h;
    reinterpret_cast<ushort4*>(lo)[i] = l;
}

// ---------------- conv weight prep ----------------
__global__ void conv_prep_kernel(const float* __restrict__ w0, const float* __restrict__ w1,
                                 const float* __restrict__ w2, const float* __restrict__ w3,
                                 unsigned short* __restrict__ Wch, unsigned short* __restrict__ Wcl) {
    int gid = blockIdx.x*256 + threadIdx.x;   // 4*3*128*128
    int c = gid & 127;
    int o = (gid >> 7) & 127;
    int kst = gid >> 14;
    int k = kst % 3, st = kst / 3;
    const float* w = (st == 0) ? w0 : (st == 1) ? w1 : (st == 2) ? w2 : w3;
    float v = (o < CH && c < CH) ? w[o*CH*3 + c*3 + k] : 0.f;
    unsigned short h, l; split1(v, &h, &l);
    Wch[gid] = h; Wcl[gid] = l;
}

// ---------------- shared weight prep ----------------
__global__ void shared_prep_kernel(const float* __restrict__ cpr1_w,
                                   const float* __restrict__ cib_w,
                                   const float* __restrict__ cpr2_w,
                                   const float* __restrict__ cma_w,
                                   const float* __restrict__ ccf_w,
                                   const float* __restrict__ cl0_w,
                                   unsigned short* __restrict__ Wcomb_h, unsigned short* __restrict__ Wcomb_l,
                                   unsigned short* __restrict__ W2h, unsigned short* __restrict__ W2l,
                                   unsigned short* __restrict__ cmah, unsigned short* __restrict__ cmal,
                                   unsigned short* __restrict__ ccfh, unsigned short* __restrict__ ccfl,
                                   unsigned short* __restrict__ cl0h, unsigned short* __restrict__ cl0l) {
    int gid = blockIdx.x*256 + threadIdx.x;   // 36864
    unsigned short h, l;
    if (gid < 8192) {               // Wcomb[o:64][c:128] = wt @ cib_w
        int o = gid >> 7, c = gid & 127;
        float v = 0.f;
        if (c < CH) {
            const float* wrow = cpr1_w + o*(2*D_);
            #pragma unroll
            for (int k = 0; k < D_; ++k) v += wrow[k]*cib_w[k*CH + c];
        }
        split1(v, &h, &l); Wcomb_h[gid] = h; Wcomb_l[gid] = l;
    } else if (gid < 12288) {       // W2[64][64]
        int idx = gid - 8192;
        split1(cpr2_w[idx], &h, &l); W2h[idx] = h; W2l[idx] = l;
    } else if (gid < 20480) {       // cma[o:128][c:64]
        int idx = gid - 12288;
        int o = idx >> 6;
        float v = (o < CH) ? cma_w[idx] : 0.f;
        split1(v, &h, &l); cmah[idx] = h; cmal[idx] = l;
    } else if (gid < 28672) {       // ccf[d:64][c:128]
        int idx = gid - 20480;
        int d = idx >> 7, c = idx & 127;
        float v = (c < CH) ? ccf_w[d*CH + c] : 0.f;
        split1(v, &h, &l); ccfh[idx] = h; ccfl[idx] = l;
    } else {                        // cl0[o:128][c:64]
        int idx = gid - 28672;
        int o = idx >> 6;
        float v = (o < CH) ? cl0_w[idx] : 0.f;
        split1(v, &h, &l); cl0h[idx] = h; cl0l[idx] = l;
    }
}

// ====== shared conv body: Tt(18 cols in LDS) -> xconv -> Xt, xc_g; then Ac ======
// Declared as macro-expanded code inside both F kernels (needs their LDS arrays).

// ---------------- F1: gather+cl0 head, then conv3+Wcomb ----------------
__global__ __launch_bounds__(512) void f1_kernel(
    const int* __restrict__ x, const float* __restrict__ emb,
    const unsigned short* __restrict__ cl0h, const unsigned short* __restrict__ cl0l,
    const float* __restrict__ cl0_b,
    const unsigned short* __restrict__ Wch, const unsigned short* __restrict__ Wcl,
    const float* __restrict__ conv_b,
    const unsigned short* __restrict__ Wcombh, const unsigned short* __restrict__ Wcombl,
    float* __restrict__ pre_d, float* __restrict__ xc_g, float* __restrict__ ac_g) {
    int b = blockIdx.x >> 4, s0 = (blockIdx.x & 15) << 4;
    int tid = threadIdx.x, w = tid >> 6, lane = tid & 63, n = lane & 15, kg = lane >> 4;

    __shared__ unsigned short Eg_h[18*72], Eg_l[18*72];
    __shared__ unsigned short Tt_h[18*136], Tt_l[18*136];
    __shared__ unsigned short Xt_h[16*136], Xt_l[16*136];

    // gather emb rows for 18 cols (s0-2..s0+15); write pre_d for own 16
    for (int idx = tid; idx < 288; idx += 512) {
        int si = idx >> 4, c4 = (idx & 15)*4;
        int s = s0 - 2 + si;
        float4 v = make_float4(0.f, 0.f, 0.f, 0.f);
        if (s >= 0) {
            int tok = x[b*SST + s];
            v = *reinterpret_cast<const float4*>(&emb[tok*D_ + c4]);
        }
        ushort4 h, l;
        split1(v.x, &h.x, &l.x); split1(v.y, &h.y, &l.y);
        split1(v.z, &h.z, &l.z); split1(v.w, &h.w, &l.w);
        *reinterpret_cast<ushort4*>(&Eg_h[si*72 + c4]) = h;
        *reinterpret_cast<ushort4*>(&Eg_l[si*72 + c4]) = l;
        if (si >= 2) {
            pre_d[(b*D_ + c4+0)*SST + s] = v.x;
            pre_d[(b*D_ + c4+1)*SST + s] = v.y;
            pre_d[(b*D_ + c4+2)*SST + s] = v.z;
            pre_d[(b*D_ + c4+3)*SST + s] = v.w;
        }
    }
    __syncthreads();

    // head: t0 = cl0 @ e + cl0_b, two overlapping col tiles -> Tt
    int ob = w*16 + kg*4;
    #pragma unroll
    for (int ct = 0; ct < 2; ++ct) {
        int si = ct*2 + n;
        f32x4 tv = {0.f, 0.f, 0.f, 0.f};
        #pragma unroll
        for (int kt = 0; kt < 2; ++kt) {
            int cc = kt*32 + kg*8;
            s8v bh = *(const s8v*)&Eg_h[si*72 + cc];
            s8v bl = *(const s8v*)&Eg_l[si*72 + cc];
            int ai = (w*16 + n)*64 + cc;
            s8v ah = *(const s8v*)&cl0h[ai];
            s8v al = *(const s8v*)&cl0l[ai];
            tv = MFMA(ah, bh, tv); tv = MFMA(ah, bl, tv); tv = MFMA(al, bh, tv);
        }
        int s = s0 - 2 + si;
        float r0 = 0.f, r1 = 0.f, r2 = 0.f, r3 = 0.f;
        if (s >= 0) {
            r0 = tv[0] + ((ob+0 < CH) ? cl0_b[ob+0] : 0.f);
            r1 = tv[1] + ((ob+1 < CH) ? cl0_b[ob+1] : 0.f);
            r2 = tv[2] + ((ob+2 < CH) ? cl0_b[ob+2] : 0.f);
            r3 = tv[3] + ((ob+3 < CH) ? cl0_b[ob+3] : 0.f);
        }
        uint2 p01 = split_pack2(r0, r1), p23 = split_pack2(r2, r3);
        *reinterpret_cast<uint2*>(&Tt_h[si*136 + ob]) = make_uint2(p01.x, p23.x);
        *reinterpret_cast<uint2*>(&Tt_l[si*136 + ob]) = make_uint2(p01.y, p23.y);
    }
    __syncthreads();

    // conv3 + relu -> Xt, xc_g
    f32x4 xcv = {0.f, 0.f, 0.f, 0.f};
    #pragma unroll
    for (int k = 0; k < 3; ++k)
        #pragma unroll
        for (int kt = 0; kt < 4; ++kt) {
            int cc = kt*32 + kg*8;
            s8v bh = *(const s8v*)&Tt_h[(n + k)*136 + cc];
            s8v bl = *(const s8v*)&Tt_l[(n + k)*136 + cc];
            int ai = (k*128 + w*16 + n)*128 + cc;
            s8v ah = *(const s8v*)&Wch[ai];
            s8v al = *(const s8v*)&Wcl[ai];
            xcv = MFMA(ah, bh, xcv); xcv = MFMA(ah, bl, xcv); xcv = MFMA(al, bh, xcv);
        }
    #pragma unroll
    for (int r = 0; r < 4; ++r) {
        float cb = (ob + r < CH) ? conv_b[ob + r] : 0.f;
        xcv[r] = fmaxf(xcv[r] + cb, 0.f);
    }
    {
        uint2 p01 = split_pack2(xcv[0], xcv[1]), p23 = split_pack2(xcv[2], xcv[3]);
        *reinterpret_cast<uint2*>(&Xt_h[n*136 + ob]) = make_uint2(p01.x, p23.x);
        *reinterpret_cast<uint2*>(&Xt_l[n*136 + ob]) = make_uint2(p01.y, p23.y);
        *reinterpret_cast<float4*>(&xc_g[(b*SST + s0 + n)*128 + ob]) =
            make_float4(xcv[0], xcv[1], xcv[2], xcv[3]);
    }
    __syncthreads();

    // Ac = Wcomb @ xconv
    if (w < 4) {
        f32x4 acc = {0.f, 0.f, 0.f, 0.f};
        #pragma unroll
        for (int kt = 0; kt < 4; ++kt) {
            int cc = kt*32 + kg*8;
            int ai = (w*16 + n)*128 + cc;
            s8v ah = *(const s8v*)&Wcombh[ai];
            s8v al = *(const s8v*)&Wcombl[ai];
            s8v bh = *(const s8v*)&Xt_h[n*136 + cc];
            s8v bl = *(const s8v*)&Xt_l[n*136 + cc];
            acc = MFMA(ah, bh, acc); acc = MFMA(ah, bl, acc); acc = MFMA(al, bh, acc);
        }
        *reinterpret_cast<float4*>(&ac_g[(b*SST + s0 + n)*64 + w*16 + kg*4]) =
            make_float4(acc[0], acc[1], acc[2], acc[3]);
    }
}

// ---------------- Fmid: t = cma@Mm + b + xc_prev head, then conv3+Wcomb ----------------
__global__ __launch_bounds__(512) void fmid_kernel(
    const unsigned short* __restrict__ Mmh, const unsigned short* __restrict__ Mml,
    const unsigned short* __restrict__ cmah, const unsigned short* __restrict__ cmal,
    const float* __restrict__ cma_b, const float* __restrict__ xc_prev,
    const unsigned short* __restrict__ Wch, const unsigned short* __restrict__ Wcl,
    const float* __restrict__ conv_b,
    const unsigned short* __restrict__ Wcombh, const unsigned short* __restrict__ Wcombl,
    float* __restrict__ xc_g, float* __restrict__ ac_g) {
    int b = blockIdx.x >> 4, s0 = (blockIdx.x & 15) << 4;
    int tid = threadIdx.x, w = tid >> 6, lane = tid & 63, n = lane & 15, kg = lane >> 4;

    __shared__ unsigned short Eg_h[18*72], Eg_l[18*72];   // Mm rows
    __shared__ unsigned short Tt_h[18*136], Tt_l[18*136];
    __shared__ unsigned short Xt_h[16*136], Xt_l[16*136];

    for (int idx = tid; idx < 288; idx += 512) {
        int si = idx >> 4, c4 = (idx & 15)*4;
        int s = s0 - 2 + si;
        uint2 h = make_uint2(0, 0), l = make_uint2(0, 0);
        if (s >= 0) {
            h = *reinterpret_cast<const uint2*>(&Mmh[(b*SST + s)*64 + c4]);
            l = *reinterpret_cast<const uint2*>(&Mml[(b*SST + s)*64 + c4]);
        }
        *reinterpret_cast<uint2*>(&Eg_h[si*72 + c4]) = h;
        *reinterpret_cast<uint2*>(&Eg_l[si*72 + c4]) = l;
    }
    __syncthreads();

    int ob = w*16 + kg*4;
    #pragma unroll
    for (int ct = 0; ct < 2; ++ct) {
        int si = ct*2 + n;
        f32x4 tv = {0.f, 0.f, 0.f, 0.f};
        #pragma unroll
        for (int kt = 0; kt < 2; ++kt) {
            int cc = kt*32 + kg*8;
            s8v bh = *(const s8v*)&Eg_h[si*72 + cc];
            s8v bl = *(const s8v*)&Eg_l[si*72 + cc];
            int ai = (w*16 + n)*64 + cc;
            s8v ah = *(const s8v*)&cmah[ai];
            s8v al = *(const s8v*)&cmal[ai];
            tv = MFMA(ah, bh, tv); tv = MFMA(ah, bl, tv); tv = MFMA(al, bh, tv);
        }
        int s = s0 - 2 + si;
        float r0 = 0.f, r1 = 0.f, r2 = 0.f, r3 = 0.f;
        if (s >= 0) {
            float4 xr = *reinterpret_cast<const float4*>(&xc_prev[(b*SST + s)*128 + ob]);
            r0 = tv[0] + ((ob+0 < CH) ? cma_b[ob+0] : 0.f) + xr.x;
            r1 = tv[1] + ((ob+1 < CH) ? cma_b[ob+1] : 0.f) + xr.y;
            r2 = tv[2] + ((ob+2 < CH) ? cma_b[ob+2] : 0.f) + xr.z;
            r3 = tv[3] + ((ob+3 < CH) ? cma_b[ob+3] : 0.f) + xr.w;
        }
        uint2 p01 = split_pack2(r0, r1), p23 = split_pack2(r2, r3);
        *reinterpret_cast<uint2*>(&Tt_h[si*136 + ob]) = make_uint2(p01.x, p23.x);
        *reinterpret_cast<uint2*>(&Tt_l[si*136 + ob]) = make_uint2(p01.y, p23.y);
    }
    __syncthreads();

    f32x4 xcv = {0.f, 0.f, 0.f, 0.f};
    #pragma unroll
    for (int k = 0; k < 3; ++k)
        #pragma unroll
        for (int kt = 0; kt < 4; ++kt) {
            int cc = kt*32 + kg*8;
            s8v bh = *(const s8v*)&Tt_h[(n + k)*136 + cc];
            s8v bl = *(const s8v*)&Tt_l[(n + k)*136 + cc];
            int ai = (k*128 + w*16 + n)*128 + cc;
            s8v ah = *(const s8v*)&Wch[ai];
            s8v al = *(const s8v*)&Wcl[ai];
            xcv = MFMA(ah, bh, xcv); xcv = MFMA(ah, bl, xcv); xcv = MFMA(al, bh, xcv);
        }
    #pragma unroll
    for (int r = 0; r < 4; ++r) {
        float cb = (ob + r < CH) ? conv_b[ob + r] : 0.f;
        xcv[r] = fmaxf(xcv[r] + cb, 0.f);
    }
    {
        uint2 p01 = split_pack2(xcv[0], xcv[1]), p23 = split_pack2(xcv[2], xcv[3]);
        *reinterpret_cast<uint2*>(&Xt_h[n*136 + ob]) = make_uint2(p01.x, p23.x);
        *reinterpret_cast<uint2*>(&Xt_l[n*136 + ob]) = make_uint2(p01.y, p23.y);
        *reinterpret_cast<float4*>(&xc_g[(b*SST + s0 + n)*128 + ob]) =
            make_float4(xcv[0], xcv[1], xcv[2], xcv[3]);
    }
    __syncthreads();

    if (w < 4) {
        f32x4 acc = {0.f, 0.f, 0.f, 0.f};
        #pragma unroll
        for (int kt = 0; kt < 4; ++kt) {
            int cc = kt*32 + kg*8;
            int ai = (w*16 + n)*128 + cc;
            s8v ah = *(const s8v*)&Wcombh[ai];
            s8v al = *(const s8v*)&Wcombl[ai];
            s8v bh = *(const s8v*)&Xt_h[n*136 + cc];
            s8v bl = *(const s8v*)&Xt_l[n*136 + cc];
            acc = MFMA(ah, bh, acc); acc = MFMA(ah, bl, acc); acc = MFMA(al, bh, acc);
        }
        *reinterpret_cast<float4*>(&ac_g[(b*SST + s0 + n)*64 + w*16 + kg*4]) =
            make_float4(acc[0], acc[1], acc[2], acc[3]);
    }
}

// ---------------- h2max: per wave one s; m = relu(max_l(W2@relu(Ac+E)) + b2) ----------------
__global__ __launch_bounds__(256) void h2max_kernel(
    const float* __restrict__ ac_g, const float* __restrict__ Eb,
    const unsigned short* __restrict__ W2h, const unsigned short* __restrict__ W2l,
    const float* __restrict__ cpr2_b,
    unsigned short* __restrict__ Mmh, unsigned short* __restrict__ Mml) {
    int b = blockIdx.x >> 6;
    int s_local = (blockIdx.x & 63)*4 + (threadIdx.x >> 6);
    int lane = threadIdx.x & 63, n = lane & 15, kg = lane >> 4;
    int bs = b*SST + s_local;

    __shared__ float El[48*68];
    for (int idx = threadIdx.x; idx < 768; idx += 256) {
        int l = idx >> 4, c4 = (idx & 15)*4;
        *reinterpret_cast<float4*>(&El[l*68 + c4]) =
            *reinterpret_cast<const float4*>(&Eb[(b*SL + l)*64 + c4]);
    }

    // Ac row of this s -> regs (wave-uniform rows, lane-varying k-octet)
    const float* ap = ac_g + bs*64;
    float4 a00 = *reinterpret_cast<const float4*>(ap + kg*8);
    float4 a01 = *reinterpret_cast<const float4*>(ap + kg*8 + 4);
    float4 a10 = *reinterpret_cast<const float4*>(ap + 32 + kg*8);
    float4 a11 = *reinterpret_cast<const float4*>(ap + 32 + kg*8 + 4);

    // W2 hi frags all preloaded; lo frags loaded per kt
    s8v a2h[4][2];
    #pragma unroll
    for (int mt = 0; mt < 4; ++mt)
        #pragma unroll
        for (int kt = 0; kt < 2; ++kt)
            a2h[mt][kt] = *(const s8v*)&W2h[(mt*16 + n)*64 + kt*32 + kg*8];

    int o_lane = ((n >> 2) << 4) + (kg << 2) + (n & 3);
    float b2_lane = cpr2_b[o_lane];
    __syncthreads();

    f32x4 acc[4][3];
    #pragma unroll
    for (int mt = 0; mt < 4; ++mt)
        #pragma unroll
        for (int lt = 0; lt < 3; ++lt)
            acc[mt][lt] = (f32x4){0.f, 0.f, 0.f, 0.f};

    #pragma unroll
    for (int kt = 0; kt < 2; ++kt) {
        int cc = kt*32 + kg*8;
        float4 aA = (kt == 0) ? a00 : a10;
        float4 aB = (kt == 0) ? a01 : a11;
        s8v a2l[4];
        #pragma unroll
        for (int mt = 0; mt < 4; ++mt)
            a2l[mt] = *(const s8v*)&W2l[(mt*16 + n)*64 + cc];
        #pragma unroll
        for (int lt = 0; lt < 3; ++lt) {
            const float* ep = &El[(lt*16 + n)*68 + cc];
            float4 e0 = *reinterpret_cast<const float4*>(ep);
            float4 e1 = *reinterpret_cast<const float4*>(ep + 4);
            float h0 = fmaxf(aA.x + e0.x, 0.f);
            float h1 = fmaxf(aA.y + e0.y, 0.f);
            float h2 = fmaxf(aA.z + e0.z, 0.f);
            float h3 = fmaxf(aA.w + e0.w, 0.f);
            float h4 = fmaxf(aB.x + e1.x, 0.f);
            float h5 = fmaxf(aB.y + e1.y, 0.f);
            float h6 = fmaxf(aB.z + e1.z, 0.f);
            float h7 = fmaxf(aB.w + e1.w, 0.f);
            uint2 q0 = split_pack2(h0, h1);
            uint2 q1 = split_pack2(h2, h3);
            uint2 q2 = split_pack2(h4, h5);
            uint2 q3 = split_pack2(h6, h7);
            union { unsigned u[4]; s8v v; } Bh, Bl;
            Bh.u[0] = q0.x; Bh.u[1] = q1.x; Bh.u[2] = q2.x; Bh.u[3] = q3.x;
            Bl.u[0] = q0.y; Bl.u[1] = q1.y; Bl.u[2] = q2.y; Bl.u[3] = q3.y;
            #pragma unroll
            for (int mt = 0; mt < 4; ++mt) {
                acc[mt][lt] = MFMA(a2h[mt][kt], Bh.v, acc[mt][lt]);
                acc[mt][lt] = MFMA(a2h[mt][kt], Bl.v, acc[mt][lt]);
                acc[mt][lt] = MFMA(a2l[mt], Bh.v, acc[mt][lt]);
            }
        }
    }

    float mx[16];
    #pragma unroll
    for (int mt = 0; mt < 4; ++mt)
        #pragma unroll
        for (int r = 0; r < 4; ++r)
            mx[mt*4 + r] = fmaxf(fmaxf(acc[mt][0][r], acc[mt][1][r]), acc[mt][2][r]);
    #pragma unroll
    for (int step = 0; step < 4; ++step) {
        int msk = 1 << step;
        #pragma unroll
        for (int i = 0; i < 16; ++i)
            mx[i] = fmaxf(mx[i], __shfl_xor(mx[i], msk));
    }
    float sel = mx[0];
    #pragma unroll
    for (int i = 1; i < 16; ++i)
        sel = (n == i) ? mx[i] : sel;
    float mval = fmaxf(sel + b2_lane, 0.f);
    unsigned short mh, ml; split1(mval, &mh, &ml);
    Mmh[bs*64 + o_lane] = mh;
    Mml[bs*64 + o_lane] = ml;
}

// ---------------- final: t4 = cma@Mm + b + xc; ccf = ccf_w@t4 + b ----------------
__global__ __launch_bounds__(256) void cmaccf_kernel(
    const unsigned short* __restrict__ Mmh, const unsigned short* __restrict__ Mml,
    const unsigned short* __restrict__ cmah, const unsigned short* __restrict__ cmal,
    const float* __restrict__ cma_b, const float* __restrict__ xc_prev,
    const unsigned short* __restrict__ ccfh, const unsigned short* __restrict__ ccfl,
    const float* __restrict__ ccf_b,
    float* __restrict__ ccf_out,
    unsigned short* __restrict__ Ahi, unsigned short* __restrict__ Alo) {
    int b = blockIdx.x >> 4, s0 = (blockIdx.x & 15) << 4;
    int tid = threadIdx.x, w = tid >> 6, lane = tid & 63, n = lane & 15, kg = lane >> 4;

    __shared__ unsigned short Mh[16*72], Ml[16*72];
    __shared__ unsigned short Th[16*136], Tl[16*136];

    for (int idx = tid; idx < 256; idx += 256) {
        int s = idx >> 4, c4 = (idx & 15)*4;
        *reinterpret_cast<uint2*>(&Mh[s*72 + c4]) =
            *reinterpret_cast<const uint2*>(&Mmh[(b*SST + s0 + s)*64 + c4]);
        *reinterpret_cast<uint2*>(&Ml[s*72 + c4]) =
            *reinterpret_cast<const uint2*>(&Mml[(b*SST + s0 + s)*64 + c4]);
    }
    __syncthreads();

    #pragma unroll
    for (int half = 0; half < 2; ++half) {
        int ob = (half*4 + w)*16 + kg*4;
        f32x4 tv = {0.f, 0.f, 0.f, 0.f};
        #pragma unroll
        for (int kt = 0; kt < 2; ++kt) {
            int cc = kt*32 + kg*8;
            s8v bh = *(const s8v*)&Mh[n*72 + cc];
            s8v bl = *(const s8v*)&Ml[n*72 + cc];
            int ai = ((half*4 + w)*16 + n)*64 + cc;
            s8v ah = *(const s8v*)&cmah[ai];
            s8v al = *(const s8v*)&cmal[ai];
            tv = MFMA(ah, bh, tv); tv = MFMA(ah, bl, tv); tv = MFMA(al, bh, tv);
        }
        int s = s0 + n;
        float4 xr = *reinterpret_cast<const float4*>(&xc_prev[(b*SST + s)*128 + ob]);
        float r0 = tv[0] + ((ob+0 < CH) ? cma_b[ob+0] : 0.f) + xr.x;
        float r1 = tv[1] + ((ob+1 < CH) ? cma_b[ob+1] : 0.f) + xr.y;
        float r2 = tv[2] + ((ob+2 < CH) ? cma_b[ob+2] : 0.f) + xr.z;
        float r3 = tv[3] + ((ob+3 < CH) ? cma_b[ob+3] : 0.f) + xr.w;
        uint2 p01 = split_pack2(r0, r1), p23 = split_pack2(r2, r3);
        *reinterpret_cast<uint2*>(&Th[n*136 + ob]) = make_uint2(p01.x, p23.x);
        *reinterpret_cast<uint2*>(&Tl[n*136 + ob]) = make_uint2(p01.y, p23.y);
    }
    __syncthreads();

    // ccf GEMM: d-tile = w
    f32x4 acc = {0.f, 0.f, 0.f, 0.f};
    #pragma unroll
    for (int kt = 0; kt < 4; ++kt) {
        int cc = kt*32 + kg*8;
        int ai = (w*16 + n)*128 + cc;
        s8v ah = *(const s8v*)&ccfh[ai];
        s8v al = *(const s8v*)&ccfl[ai];
        s8v bh = *(const s8v*)&Th[n*136 + cc];
        s8v bl = *(const s8v*)&Tl[n*136 + cc];
        acc = MFMA(ah, bh, acc); acc = MFMA(ah, bl, acc); acc = MFMA(al, bh, acc);
    }
    int d0 = w*16 + kg*4, s = s0 + n;
    float v0 = acc[0] + ccf_b[d0+0];
    float v1 = acc[1] + ccf_b[d0+1];
    float v2 = acc[2] + ccf_b[d0+2];
    float v3 = acc[3] + ccf_b[d0+3];
    ccf_out[(b*D_ + d0+0)*SST + s] = v0;
    ccf_out[(b*D_ + d0+1)*SST + s] = v1;
    ccf_out[(b*D_ + d0+2)*SST + s] = v2;
    ccf_out[(b*D_ + d0+3)*SST + s] = v3;
    uint2 p01 = split_pack2(v0, v1), p23 = split_pack2(v2, v3);
    *reinterpret_cast<uint2*>(&Ahi[(b*SST + s)*64 + d0]) = make_uint2(p01.x, p23.x);
    *reinterpret_cast<uint2*>(&Alo[(b*SST + s)*64 + d0]) = make_uint2(p01.y, p23.y);
}

// ---------------- logits: MFMA bf16 hi/lo GEMM ----------------
__global__ __launch_bounds__(256) void logits_mfma_kernel(
    const unsigned short* __restrict__ Ahi,
    const unsigned short* __restrict__ Alo,
    const unsigned short* __restrict__ Bhi,
    const unsigned short* __restrict__ Blo,
    const float* __restrict__ fffb,
    float* __restrict__ out) {
    int ntile = blockIdx.x & 127;
    int mtile = blockIdx.x >> 7;
    int wid = threadIdx.x >> 6;
    int lane = threadIdx.x & 63;
    int wm = wid >> 1, wn = wid & 1;
    int m0 = mtile*128 + wm*64;
    int v0 = ntile*128 + wn*64;
    int row16 = lane & 15, kg = lane >> 4;

    const short* Ah = (const short*)Ahi;
    const short* Al = (const short*)Alo;
    const short* Bh = (const short*)Bhi;
    const short* Bl = (const short*)Blo;

    f32x4 acc[4][4];
    #pragma unroll
    for (int mi = 0; mi < 4; ++mi)
        #pragma unroll
        for (int ni = 0; ni < 4; ++ni)
            acc[mi][ni] = (f32x4){0.f, 0.f, 0.f, 0.f};

    #pragma unroll
    for (int kk = 0; kk < 2; ++kk) {
        int koff = kk*32 + kg*8;
        s8v ah[4], al[4], bh[4], bl[4];
        #pragma unroll
        for (int mi = 0; mi < 4; ++mi) {
            int r = (m0 + mi*16 + row16)*D_ + koff;
            ah[mi] = *reinterpret_cast<const s8v*>(Ah + r);
            al[mi] = *reinterpret_cast<const s8v*>(Al + r);
        }
        #pragma unroll
        for (int ni = 0; ni < 4; ++ni) {
            int r = (v0 + ni*16 + row16)*D_ + koff;
            bh[ni] = *reinterpret_cast<const s8v*>(Bh + r);
            bl[ni] = *reinterpret_cast<const s8v*>(Bl + r);
        }
        #pragma unroll
        for (int mi = 0; mi < 4; ++mi)
            #pragma unroll
            for (int ni = 0; ni < 4; ++ni) {
                acc[mi][ni] = MFMA(ah[mi], bh[ni], acc[mi][ni]);
                acc[mi][ni] = MFMA(ah[mi], bl[ni], acc[mi][ni]);
                acc[mi][ni] = MFMA(al[mi], bh[ni], acc[mi][ni]);
            }
    }

    #pragma unroll
    for (int ni = 0; ni < 4; ++ni) {
        int v = v0 + ni*16 + row16;
        float fb = fffb[v];
        #pragma unroll
        for (int mi = 0; mi < 4; ++mi) {
            int mbase = m0 + mi*16 + kg*4;
            #pragma unroll
            for (int r = 0; r < 4; ++r) {
                __builtin_nontemporal_store(acc[mi][ni][r] + fb,
                    &out[(size_t)(mbase + r)*VOCAB + v]);
            }
        }
    }
}

extern "C" void kernel_launch(void* const* d_in, const int* in_sizes, int n_in,
                              void* d_out, int out_size, void* d_ws, size_t ws_size,
                              hipStream_t stream) {
    const int*   x     = (const int*)d_in[0];
    const float* ees   = (const float*)d_in[1];
    const float* emb   = (const float*)d_in[2];
    const float* cl0_w = (const float*)d_in[3];
    const float* cl0_b = (const float*)d_in[4];
    const float* cl1_w = (const float*)d_in[5];
    const float* cl1_b = (const float*)d_in[6];
    const float* claa_w= (const float*)d_in[7];
    const float* claa_b= (const float*)d_in[8];
    const float* clfa_w= (const float*)d_in[9];
    const float* clfa_b= (const float*)d_in[10];
    const float* ccac_w= (const float*)d_in[11];
    const float* ccac_b= (const float*)d_in[12];
    const float* cib_w = (const float*)d_in[13];
    const float* cib_b = (const float*)d_in[14];
    const float* cpr1_w= (const float*)d_in[15];
    const float* cpr1_b= (const float*)d_in[16];
    const float* cpr2_w= (const float*)d_in[17];
    const float* cpr2_b= (const float*)d_in[18];
    const float* cma_w = (const float*)d_in[19];
    const float* cma_b = (const float*)d_in[20];
    const float* ccf_w = (const float*)d_in[21];
    const float* ccf_b = (const float*)d_in[22];
    const float* fff_b = (const float*)d_in[23];

    float* out = (float*)d_out;
    float* out_pre = out + OUT0_ELEMS;
    float* out_ccf = out_pre + OUT1_ELEMS;

    // logits inputs in d_ws (alive while logits overwrites out0)
    unsigned short* EmbHi = (unsigned short*)d_ws;
    unsigned short* EmbLo = EmbHi + VOCAB*D_;
    unsigned short* Ahi   = EmbLo + VOCAB*D_;
    unsigned short* Alo   = Ahi + B_*SST*D_;

    // pre-logits scratch inside out0 (consumed before logits runs)
    char* sc = (char*)d_out + (size_t)16*1024*1024;
    float*          Eb    = (float*)sc;            sc += B_*SL*D_*4;        // 196608
    unsigned short* Wch   = (unsigned short*)sc;   sc += 4*3*128*128*2;
    unsigned short* Wcl   = (unsigned short*)sc;   sc += 4*3*128*128*2;
    unsigned short* Wcombh= (unsigned short*)sc;   sc += 64*128*2;
    unsigned short* Wcombl= (unsigned short*)sc;   sc += 64*128*2;
    unsigned short* W2h   = (unsigned short*)sc;   sc += 64*64*2;
    unsigned short* W2l   = (unsigned short*)sc;   sc += 64*64*2;
    unsigned short* cmah  = (unsigned short*)sc;   sc += 128*64*2;
    unsigned short* cmal  = (unsigned short*)sc;   sc += 128*64*2;
    unsigned short* ccfh  = (unsigned short*)sc;   sc += 64*128*2;
    unsigned short* ccfl  = (unsigned short*)sc;   sc += 64*128*2;
    unsigned short* cl0h  = (unsigned short*)sc;   sc += 128*64*2;
    unsigned short* cl0l  = (unsigned short*)sc;   sc += 128*64*2;
    float*          xc_a  = (float*)sc;            sc += (size_t)B_*SST*128*4;
    float*          xc_b  = (float*)sc;            sc += (size_t)B_*SST*128*4;
    float*          ac_g  = (float*)sc;            sc += (size_t)B_*SST*64*4;
    unsigned short* Mmh   = (unsigned short*)sc;   sc += B_*SST*64*2;
    unsigned short* Mml   = (unsigned short*)sc;   sc += B_*SST*64*2;

    // prep
    conv_prep_kernel<<<768, 256, 0, stream>>>(cl1_w, claa_w, clfa_w, ccac_w, Wch, Wcl);
    shared_prep_kernel<<<144, 256, 0, stream>>>(cpr1_w, cib_w, cpr2_w, cma_w, ccf_w, cl0_w,
        Wcombh, Wcombl, W2h, W2l, cmah, cmal, ccfh, ccfl, cl0h, cl0l);
    emb2bf_kernel<<<VOCAB*D_/4/256, 256, 0, stream>>>(emb, EmbHi, EmbLo);
    e_kernel<<<B_*SL, 64, 0, stream>>>(ees, cpr1_w, cpr1_b, cib_b, Eb);

    const int WCS = 3*128*128;
    // stage 1
    f1_kernel<<<256, 512, 0, stream>>>(x, emb, cl0h, cl0l, cl0_b,
        Wch + 0*WCS, Wcl + 0*WCS, cl1_b, Wcombh, Wcombl, out_pre, xc_a, ac_g);
    h2max_kernel<<<1024, 256, 0, stream>>>(ac_g, Eb, W2h, W2l, cpr2_b, Mmh, Mml);
    // stage 2
    fmid_kernel<<<256, 512, 0, stream>>>(Mmh, Mml, cmah, cmal, cma_b, xc_a,
        Wch + 1*WCS, Wcl + 1*WCS, claa_b, Wcombh, Wcombl, xc_b, ac_g);
    h2max_kernel<<<1024, 256, 0, stream>>>(ac_g, Eb, W2h, W2l, cpr2_b, Mmh, Mml);
    // stage 3
    fmid_kernel<<<256, 512, 0, stream>>>(Mmh, Mml, cmah, cmal, cma_b, xc_b,
        Wch + 2*WCS, Wcl + 2*WCS, clfa_b, Wcombh, Wcombl, xc_a, ac_g);
    h2max_kernel<<<1024, 256, 0, stream>>>(ac_g, Eb, W2h, W2l, cpr2_b, Mmh, Mml);
    // stage 4
    fmid_kernel<<<256, 512, 0, stream>>>(Mmh, Mml, cmah, cmal, cma_b, xc_a,
        Wch + 3*WCS, Wcl + 3*WCS, ccac_b, Wcombh, Wcombl, xc_b, ac_g);
    h2max_kernel<<<1024, 256, 0, stream>>>(ac_g, Eb, W2h, W2l, cpr2_b, Mmh, Mml);

    // epilogue: t4 + ccf fused, then logits
    cmaccf_kernel<<<256, 256, 0, stream>>>(Mmh, Mml, cmah, cmal, cma_b, xc_b,
        ccfh, ccfl, ccf_b, out_ccf, Ahi, Alo);
    logits_mfma_kernel<<<(B_*SST/128)*(VOCAB/128), 256, 0, stream>>>(
        Ahi, Alo, EmbHi, EmbLo, fff_b, out);
}